// Round 10
// baseline (865.835 us; speedup 1.0000x reference)
//
#include <hip/hip_runtime.h>
#include <math.h>

#define T_  1024
#define B_  4
#define D_  512
#define H_  8
#define DH_ 64
#define DI_ 2048
#define V_  256
#define L_  8
#define S_  256   // segments

typedef _Float16 f16;
typedef f16   f16x8 __attribute__((ext_vector_type(8)));
typedef float f32x4 __attribute__((ext_vector_type(4)));

// attention score scale folded with log2(e): softmax exp(x*0.125) == exp2(x*SC)
#define SC_ 0.18033688f

__device__ __forceinline__ void gload16(const void* g, void* l) {
    __builtin_amdgcn_global_load_lds(
        (const __attribute__((address_space(1))) void*)g,
        (__attribute__((address_space(3))) void*)l, 16, 0, 0);
}

// Q=1024 task table: 24 tasks/(b,n), breadth-first CU triples sum to 17.
__constant__ int cIT[24] = {15,15,14,13,12,11,10, 9,  8, 7,14, 6,13, 5,12, 4,  8, 0, 9, 1,10, 2,11, 3};
__constant__ int cT0[24] = { 0, 8, 0, 0, 0, 0, 0, 0,  0, 0, 8, 0, 8, 0, 8, 0,  8, 0, 8, 0, 8, 0, 8, 0};
__constant__ int cT1[24] = { 8,16, 8, 8, 8, 8, 8, 8,  8, 8,15, 7,14, 6,13, 5,  9, 1,10, 2,11, 3,12, 4};
// Q=257 task table: 8 tasks/(b,n) = 256 blocks = 1/CU.
__constant__ int cIT2[8] = {4,4,3,3,2,2,1,0};
__constant__ int cT02[8] = {0,3,0,2,0,2,0,0};
__constant__ int cT12[8] = {3,5,2,4,2,3,2,1};

// ---------------------------------------------------------------------------
__global__ __launch_bounds__(256) void k_f2h(const float* __restrict__ s,
                                             f16* __restrict__ d, int n) {
    int i = (blockIdx.x * 256 + threadIdx.x) * 4;
    int stride = gridDim.x * 1024;
    for (; i < n; i += stride) {
        float4 v = *(const float4*)(s + i);
        d[i + 0] = (f16)v.x; d[i + 1] = (f16)v.y;
        d[i + 2] = (f16)v.z; d[i + 3] = (f16)v.w;
    }
}

// ---------------------------------------------------------------------------
__global__ __launch_bounds__(256) void k_embed(const int* __restrict__ data,
                                               const float* __restrict__ emb,
                                               float* __restrict__ x,
                                               f16* __restrict__ xh) {
    int idx = blockIdx.x * 256 + threadIdx.x;
    if (idx >= T_ * B_ * D_) return;
    int d  = idx & (D_ - 1);
    int tb = idx >> 9;
    float v = emb[(size_t)data[tb] * D_ + d];
    x[idx] = v; xh[idx] = (f16)v;
}

// ---------------------------------------------------------------------------
__global__ __launch_bounds__(256) void k_posemb(f16* __restrict__ r, int qlen) {
    int p = blockIdx.x;
    int k = threadIdx.x;
    float pos = (float)(qlen - 1 - p);
    float inv = powf(10000.f, -((float)k) / 256.f);
    float ang = pos * inv;
    r[(size_t)p * D_ + k]       = (f16)sinf(ang);
    r[(size_t)p * D_ + 256 + k] = (f16)cosf(ang);
}

// ---------------------------------------------------------------------------
// MFMA fp16 GEMM: 2-phase double-buffered LDS (T3-minimum schedule): issue
// next-tile global_load_lds BEFORE current MFMA; one barrier per K-iter.
// XCD-chunked swizzle; parameterized tile. X has row stride lda.
template<int BM, int BN, int OUT16, int ACT>
__global__ __launch_bounds__(256) void k_gemm(const f16* __restrict__ X, int lda,
                                              const f16* __restrict__ W,
                                              const float* __restrict__ bias,
                                              void* __restrict__ Yv,
                                              int M, int N, int K) {
    __shared__ f16 As[2][BM * 64];
    __shared__ f16 Bs[2][BN * 64];
    const int tid = threadIdx.x, w = tid >> 6, lane = tid & 63;
    const int l16 = lane & 15, lg = lane >> 4;
    int nwg = gridDim.x * gridDim.y;
    int bid = blockIdx.y * gridDim.x + blockIdx.x;
    if ((nwg & 7) == 0) bid = (bid & 7) * (nwg >> 3) + (bid >> 3);   // XCD chunked
    const int bm = (bid % gridDim.x) * BM, bn = (bid / gridDim.x) * BN;
    const int lrow = lane >> 3, lcol = (lane & 7) * 8;
    constexpr int AI = BM / 32;
    constexpr int BI = BN / 32;
    constexpr int MI = (BN == 128) ? 4 : BM / 32;
    constexpr int NJ = 2;
    const int rbase = (BN == 128) ? 0 : (w >> 1) * (BM / 2);
    const int cbase = (BN == 128) ? w * 32 : (w & 1) * 32;
    const f32x4 z4 = {0.f, 0.f, 0.f, 0.f};
    f32x4 acc[MI][NJ];
    #pragma unroll
    for (int i = 0; i < MI; ++i)
        #pragma unroll
        for (int j = 0; j < NJ; ++j) acc[i][j] = z4;

    auto stage = [&](int buf, int k0) {
        #pragma unroll
        for (int u = 0; u < AI; ++u) {
            int rb = w * (BM / 4) + u * 8;
            gload16(X + (size_t)(bm + rb + lrow) * lda + k0 + lcol, &As[buf][rb * 64]);
        }
        #pragma unroll
        for (int u = 0; u < BI; ++u) {
            int rb = w * (BN / 4) + u * 8;
            gload16(W + (size_t)(bn + rb + lrow) * K + k0 + lcol, &Bs[buf][rb * 64]);
        }
    };

    stage(0, 0);
    __syncthreads();                       // drain prologue loads
    int cur = 0;
    for (int k0 = 0; k0 < K; k0 += 64) {
        if (k0 + 64 < K) stage(cur ^ 1, k0 + 64);   // loads fly under MFMA
        __builtin_amdgcn_s_setprio(1);
        #pragma unroll
        for (int h = 0; h < 2; ++h) {
            f16x8 af[MI], bf[NJ];
            #pragma unroll
            for (int i = 0; i < MI; ++i)
                af[i] = *(const f16x8*)&As[cur][(rbase + i * 16 + l16) * 64 + h * 32 + lg * 8];
            #pragma unroll
            for (int j = 0; j < NJ; ++j)
                bf[j] = *(const f16x8*)&Bs[cur][(cbase + j * 16 + l16) * 64 + h * 32 + lg * 8];
            #pragma unroll
            for (int i = 0; i < MI; ++i)
                #pragma unroll
                for (int j = 0; j < NJ; ++j)
                    acc[i][j] = __builtin_amdgcn_mfma_f32_16x16x32_f16(af[i], bf[j], acc[i][j], 0, 0, 0);
        }
        __builtin_amdgcn_s_setprio(0);
        __syncthreads();                   // next-tile loads done; readers done
        cur ^= 1;
    }
    #pragma unroll
    for (int i = 0; i < MI; ++i) {
        #pragma unroll
        for (int r = 0; r < 4; ++r) {
            int row = bm + rbase + i * 16 + lg * 4 + r;
            if (row >= M) continue;
            int colb = bn + cbase + l16;
            #pragma unroll
            for (int j = 0; j < NJ; ++j) {
                float v = acc[i][j][r];
                if (bias) v += bias[colb + j * 16];
                if (ACT) v = fmaxf(v, 0.f);
                if (OUT16) ((f16*)Yv)[(size_t)row * N + colb + j * 16] = (f16)v;
                else       ((float*)Yv)[(size_t)row * N + colb + j * 16] = v;
            }
        }
    }
}

// ---------------------------------------------------------------------------
// Add(f16) + LayerNorm, one WAVE per row, 4 rows/block.
__global__ __launch_bounds__(256) void k_ln(float* __restrict__ x,
                                            const f16* __restrict__ add,
                                            const float* __restrict__ g,
                                            const float* __restrict__ b,
                                            f16* __restrict__ xh, int rows) {
    int row = blockIdx.x * 4 + (threadIdx.x >> 6);
    if (row >= rows) return;
    int lane = threadIdx.x & 63;
    float* xr = x + (size_t)row * D_ + lane * 8;
    float v[8];
    {
        float4 a0 = *(const float4*)xr;
        float4 a1 = *(const float4*)(xr + 4);
        v[0] = a0.x; v[1] = a0.y; v[2] = a0.z; v[3] = a0.w;
        v[4] = a1.x; v[5] = a1.y; v[6] = a1.z; v[7] = a1.w;
    }
    if (add) {
        f16x8 a = *(const f16x8*)(add + (size_t)row * D_ + lane * 8);
        #pragma unroll
        for (int u = 0; u < 8; ++u) v[u] += (float)a[u];
    }
    float s = 0.f, sq = 0.f;
    #pragma unroll
    for (int u = 0; u < 8; ++u) { s += v[u]; sq += v[u] * v[u]; }
    #pragma unroll
    for (int off = 1; off < 64; off <<= 1) {
        s  += __shfl_xor(s,  off, 64);
        sq += __shfl_xor(sq, off, 64);
    }
    float mean = s * (1.f / (float)D_);
    float var  = sq * (1.f / (float)D_) - mean * mean;
    float rs   = rsqrtf(var + 1e-5f);
    const float* gp = g + lane * 8;
    const float* bp = b + lane * 8;
    float4 g0 = *(const float4*)gp, g1 = *(const float4*)(gp + 4);
    float4 b0 = *(const float4*)bp, b1 = *(const float4*)(bp + 4);
    float gg[8] = {g0.x, g0.y, g0.z, g0.w, g1.x, g1.y, g1.z, g1.w};
    float bb[8] = {b0.x, b0.y, b0.z, b0.w, b1.x, b1.y, b1.z, b1.w};
    float o[8];
    #pragma unroll
    for (int u = 0; u < 8; ++u) o[u] = (v[u] - mean) * rs * gg[u] + bb[u];
    *(float4*)xr       = make_float4(o[0], o[1], o[2], o[3]);
    *(float4*)(xr + 4) = make_float4(o[4], o[5], o[6], o[7]);
    f16x8 hv;
    #pragma unroll
    for (int u = 0; u < 8; ++u) hv[u] = (f16)o[u];
    *(f16x8*)(xh + (size_t)row * D_ + lane * 8) = hv;
}

// ---------------------------------------------------------------------------
// Fused downsample (mean-pool + null row) + LayerNorm. Wave per output row.
__global__ __launch_bounds__(256) void k_downln(const float* __restrict__ x,
                                                const float* __restrict__ nullg,
                                                const float* __restrict__ g,
                                                const float* __restrict__ bi,
                                                float* __restrict__ xs,
                                                f16* __restrict__ xsh) {
    int row = blockIdx.x * 4 + (threadIdx.x >> 6);
    if (row >= (S_ + 1) * B_) return;
    int lane = threadIdx.x & 63;
    int s = row >> 2, b = row & 3;
    float v[8];
    if (s == 0) {
        const float* np = nullg + lane * 8;
        float4 a0 = *(const float4*)np, a1 = *(const float4*)(np + 4);
        v[0] = a0.x; v[1] = a0.y; v[2] = a0.z; v[3] = a0.w;
        v[4] = a1.x; v[5] = a1.y; v[6] = a1.z; v[7] = a1.w;
    } else {
        int t0 = (s - 1) * 4;
        #pragma unroll
        for (int u = 0; u < 8; ++u) v[u] = 0.f;
        #pragma unroll
        for (int k = 0; k < 4; ++k) {
            const float* xp = x + ((size_t)(t0 + k) * B_ + b) * D_ + lane * 8;
            float4 a0 = *(const float4*)xp, a1 = *(const float4*)(xp + 4);
            v[0] += a0.x; v[1] += a0.y; v[2] += a0.z; v[3] += a0.w;
            v[4] += a1.x; v[5] += a1.y; v[6] += a1.z; v[7] += a1.w;
        }
        #pragma unroll
        for (int u = 0; u < 8; ++u) v[u] *= 0.25f;
    }
    float sm = 0.f, sq = 0.f;
    #pragma unroll
    for (int u = 0; u < 8; ++u) { sm += v[u]; sq += v[u] * v[u]; }
    #pragma unroll
    for (int off = 1; off < 64; off <<= 1) {
        sm += __shfl_xor(sm, off, 64);
        sq += __shfl_xor(sq, off, 64);
    }
    float mean = sm * (1.f / (float)D_);
    float var  = sq * (1.f / (float)D_) - mean * mean;
    float rs   = rsqrtf(var + 1e-5f);
    float o[8];
    #pragma unroll
    for (int u = 0; u < 8; ++u)
        o[u] = (v[u] - mean) * rs * g[lane * 8 + u] + bi[lane * 8 + u];
    float* xp = xs + (size_t)row * D_ + lane * 8;
    *(float4*)xp       = make_float4(o[0], o[1], o[2], o[3]);
    *(float4*)(xp + 4) = make_float4(o[4], o[5], o[6], o[7]);
    f16x8 hv;
    #pragma unroll
    for (int u = 0; u < 8; ++u) hv[u] = (f16)o[u];
    *(f16x8*)(xsh + (size_t)row * D_ + lane * 8) = hv;
}

__global__ __launch_bounds__(256) void k_up(float* __restrict__ x,
                                            const float* __restrict__ xs,
                                            f16* __restrict__ xh) {
    int idx = blockIdx.x * 256 + threadIdx.x;
    if (idx >= T_ * B_ * D_) return;
    int d  = idx & (D_ - 1);
    int tb = idx >> 9;
    int t = tb >> 2, b = tb & 3;
    int seg = (t + 1) >> 2;
    float v = x[idx] + xs[((size_t)seg * B_ + b) * D_ + d];
    x[idx] = v; xh[idx] = (f16)v;
}

// ---------------------------------------------------------------------------
// MFMA flash attention v7: balanced task tables (Q=1024: 24 tasks, CU-sum=17;
// Q=257: 8 tasks = 1/CU), deferred softmax in exp2 domain (scale*log2e folded
// into Q staging), swizzled LDS, circular RK window, 1-deep prefetch,
// XCD-local mapping. Split partials combine by plain addition (k_comb).
__global__ __launch_bounds__(256) void k_attn(f16* __restrict__ qkv,
                                              const f16* __restrict__ rkb,
                                              int ldr,
                                              const float* __restrict__ rwb,
                                              const float* __restrict__ rrb,
                                              int Q, float* __restrict__ part) {
    __shared__ f16 RKs[192 * 64];
    __shared__ f16 Ks[64 * 64];
    __shared__ f16 Vt[64 * 72];
    __shared__ f16 Pl[4][16 * 72];
    f16* Qw = RKs;
    f16* Qr = RKs + 4096;

    int it, t0, t1, b, n;
    bool partial;
    int idxp;
    {
        int p = blockIdx.y * gridDim.x + blockIdx.x;
        int xcd = p & 7, qq = p >> 3;
        b = xcd >> 1;
        n = (xcd & 1) * 4 + (qq & 3);
        int slot = qq >> 2;
        if (Q == 1024) {
            it = cIT[slot]; t0 = cT0[slot]; t1 = cT1[slot];
            partial = (it >= 8);
            idxp = (b * 8 + n) * 8 + (it - 8);
        } else {           // Q == 257, grid (8,32)
            it = cIT2[slot]; t0 = cT02[slot]; t1 = cT12[slot];
            partial = (it >= 2);
            idxp = (b * 8 + n) * 3 + (it - 2);
        }
    }
    const int i0 = it * 64;
    const int tid = threadIdx.x, w = tid >> 6, lane = tid & 63;
    const int l16 = lane & 15, lg = lane >> 4;
    const int xsw = (l16 & 7) << 3;
    const int gr8 = lane >> 3;
    const int gsl = ((lane & 7) ^ gr8) * 8;
    const int vjj = tid >> 2, vdb = (tid & 3) * 16;
    const int wb = 48 - w * 16;
    const f32x4 z4 = {0.f, 0.f, 0.f, 0.f};

    {   // stage Q (+biases, ×SC_) into RK alias, swizzled
        int row = tid >> 2, dq = (tid & 3) * 16;
        const f16* qp = qkv + ((size_t)(i0 + row) * B_ + b) * 1536 + n * 64 + dq;
        f16x8 q0 = *(const f16x8*)qp, q1 = *(const f16x8*)(qp + 8);
        int rsw = (row & 7) << 3;
        #pragma unroll
        for (int u = 0; u < 8; ++u) {
            float qa = (float)q0[u], qb2 = (float)q1[u];
            Qw[row * 64 + ((dq + u) ^ rsw)]     = (f16)((qa + rwb[n * 64 + dq + u]) * SC_);
            Qw[row * 64 + ((dq + 8 + u) ^ rsw)] = (f16)((qb2 + rwb[n * 64 + dq + 8 + u]) * SC_);
            Qr[row * 64 + ((dq + u) ^ rsw)]     = (f16)((qa + rrb[n * 64 + dq + u]) * SC_);
            Qr[row * 64 + ((dq + 8 + u) ^ rsw)] = (f16)((qb2 + rrb[n * 64 + dq + 8 + u]) * SC_);
        }
    }
    __syncthreads();
    f16x8 aqw[2], aqr[2];
    #pragma unroll
    for (int h = 0; h < 2; ++h) {
        aqw[h] = *(const f16x8*)&Qw[(w * 16 + l16) * 64 + ((h * 32 + lg * 8) ^ xsw)];
        aqr[h] = *(const f16x8*)&Qr[(w * 16 + l16) * 64 + ((h * 32 + lg * 8) ^ xsw)];
    }
    __syncthreads();

    const long long pb = (long long)Q - 64 - i0;
    #pragma unroll
    for (int u = 0; u < 4; ++u) {
        int rb = w * 32 + u * 8;
        long long p = pb + t0 * 64 + rb + gr8;
        gload16(rkb + p * ldr + n * 64 + gsl, &RKs[rb * 64]);
    }
    #pragma unroll
    for (int u = 0; u < 2; ++u) {
        int rb = w * 16 + u * 8;
        gload16(qkv + ((size_t)(t0 * 64 + rb + gr8) * B_ + b) * 1536 + 512 + n * 64 + gsl,
                &Ks[rb * 64]);
    }
    f16x8 vr0, vr1;
    {
        const f16* vp = qkv + ((size_t)(t0 * 64 + vjj) * B_ + b) * 1536 + 1024 + n * 64 + vdb;
        vr0 = *(const f16x8*)vp; vr1 = *(const f16x8*)(vp + 8);
    }

    f32x4 acc[4]; acc[0] = z4; acc[1] = z4; acc[2] = z4; acc[3] = z4;
    float psum[4] = {0.f, 0.f, 0.f, 0.f};
    int base = 0;

    for (int t = t0; t < t1; ++t) {
        const int j0 = t * 64;
        __syncthreads();   // A
        #pragma unroll
        for (int u = 0; u < 8; ++u) {
            Vt[(vdb + u) * 72 + (vjj ^ ((u & 7) << 3))]     = vr0[u];
            Vt[(vdb + 8 + u) * 72 + (vjj ^ ((u & 7) << 3))] = vr1[u];
        }
        if (t + 1 < t1) {
            int sb = base + 128; if (sb >= 192) sb -= 192;
            #pragma unroll
            for (int u = 0; u < 2; ++u) {
                int rb = w * 16 + u * 8;
                long long p = pb + j0 + 128 + rb + gr8;
                gload16(rkb + p * ldr + n * 64 + gsl, &RKs[(sb + rb) * 64]);
            }
        }
        f32x4 s1[4]; s1[0] = z4; s1[1] = z4; s1[2] = z4; s1[3] = z4;
        __builtin_amdgcn_s_setprio(1);
        #pragma unroll
        for (int f = 0; f < 4; ++f)
            #pragma unroll
            for (int h = 0; h < 2; ++h) {
                f16x8 bv = *(const f16x8*)&Ks[(f * 16 + l16) * 64 + ((h * 32 + lg * 8) ^ xsw)];
                s1[f] = __builtin_amdgcn_mfma_f32_16x16x32_f16(aqw[h], bv, s1[f], 0, 0, 0);
            }
        __builtin_amdgcn_s_setprio(0);
        if (t + 1 < t1) {
            const f16* vp = qkv + ((size_t)(j0 + 64 + vjj) * B_ + b) * 1536 + 1024 + n * 64 + vdb;
            vr0 = *(const f16x8*)vp; vr1 = *(const f16x8*)(vp + 8);
        }
        f32x4 s2[5]; s2[0] = z4; s2[1] = z4; s2[2] = z4; s2[3] = z4; s2[4] = z4;
        __builtin_amdgcn_s_setprio(1);
        #pragma unroll
        for (int f = 0; f < 5; ++f) {
            int slot = base + wb + f * 16 + l16; if (slot >= 192) slot -= 192;
            #pragma unroll
            for (int h = 0; h < 2; ++h) {
                f16x8 bv = *(const f16x8*)&RKs[slot * 64 + ((h * 32 + lg * 8) ^ xsw)];
                s2[f] = __builtin_amdgcn_mfma_f32_16x16x32_f16(aqr[h], bv, s2[f], 0, 0, 0);
            }
        }
        __builtin_amdgcn_s_setprio(0);
        // deferred softmax in exp2 domain; lane-local row-sum
        #pragma unroll
        for (int r = 0; r < 4; ++r) {
            const int q = lg * 4 + r;
            const int iq = i0 + w * 16 + q;
            const int src = (lane & 48) | ((l16 + 15 - q) & 15);
            float g0 = __shfl(s2[0][r], src, 64);
            float g1 = __shfl(s2[1][r], src, 64);
            float g2 = __shfl(s2[2][r], src, 64);
            float g3 = __shfl(s2[3][r], src, 64);
            float g4 = __shfl(s2[4][r], src, 64);
            const bool hi = l16 > q;
            float sv[4];
            sv[0] = s1[0][r] + (hi ? g1 : g0);
            sv[1] = s1[1][r] + (hi ? g2 : g1);
            sv[2] = s1[2][r] + (hi ? g3 : g2);
            sv[3] = s1[3][r] + (hi ? g4 : g3);
            #pragma unroll
            for (int h = 0; h < 4; ++h) {
                int j = j0 + h * 16 + l16;
                if (j > iq || j >= Q) sv[h] = -1e30f;
            }
            float p0 = exp2f(sv[0]), p1 = exp2f(sv[1]);
            float p2 = exp2f(sv[2]), p3 = exp2f(sv[3]);
            psum[r] += (p0 + p1) + (p2 + p3);
            Pl[w][q * 72 + l16]      = (f16)p0;
            Pl[w][q * 72 + 16 + l16] = (f16)p1;
            Pl[w][q * 72 + 32 + l16] = (f16)p2;
            Pl[w][q * 72 + 48 + l16] = (f16)p3;
        }
        __syncthreads();   // B
        f16x8 pa0 = *(const f16x8*)&Pl[w][l16 * 72 + lg * 8];
        f16x8 pa1 = *(const f16x8*)&Pl[w][l16 * 72 + 32 + lg * 8];
        __builtin_amdgcn_s_setprio(1);
        #pragma unroll
        for (int f = 0; f < 4; ++f) {
            f16x8 bv0 = *(const f16x8*)&Vt[(f * 16 + l16) * 72 + ((lg * 8) ^ xsw)];
            acc[f] = __builtin_amdgcn_mfma_f32_16x16x32_f16(pa0, bv0, acc[f], 0, 0, 0);
            f16x8 bv1 = *(const f16x8*)&Vt[(f * 16 + l16) * 72 + ((32 + lg * 8) ^ xsw)];
            acc[f] = __builtin_amdgcn_mfma_f32_16x16x32_f16(pa1, bv1, acc[f], 0, 0, 0);
        }
        __builtin_amdgcn_s_setprio(0);
        if (t + 1 < t1) {
            #pragma unroll
            for (int u = 0; u < 2; ++u) {
                int rb = w * 16 + u * 8;
                gload16(qkv + ((size_t)(j0 + 64 + rb + gr8) * B_ + b) * 1536 + 512 + n * 64 + gsl,
                        &Ks[rb * 64]);
            }
        }
        base += 64; if (base >= 192) base -= 192;
    }
    if (partial) {
        float* Pp = part + (size_t)idxp * 8320 + (t0 ? 4160 : 0);
        #pragma unroll
        for (int r = 0; r < 4; ++r) {
            float ps = psum[r];
            ps += __shfl_xor(ps, 1, 64);
            ps += __shfl_xor(ps, 2, 64);
            ps += __shfl_xor(ps, 4, 64);
            ps += __shfl_xor(ps, 8, 64);
            int row = w * 16 + lg * 4 + r;
            #pragma unroll
            for (int f = 0; f < 4; ++f)
                Pp[row * 64 + f * 16 + l16] = acc[f][r];
            if (l16 == 0) Pp[4096 + row] = ps;
        }
    } else {
        #pragma unroll
        for (int r = 0; r < 4; ++r) {
            float ps = psum[r];
            ps += __shfl_xor(ps, 1, 64);
            ps += __shfl_xor(ps, 2, 64);
            ps += __shfl_xor(ps, 4, 64);
            ps += __shfl_xor(ps, 8, 64);
            int i = i0 + w * 16 + lg * 4 + r;
            if (i < Q) {
                float inv = 1.f / ps;
                f16* op = qkv + ((size_t)i * B_ + b) * 1536 + n * 64;
                #pragma unroll
                for (int f = 0; f < 4; ++f)
                    op[f * 16 + l16] = (f16)(acc[f][r] * inv);
            }
        }
    }
}

// ---------------------------------------------------------------------------
// Combine split-attention partials: out = (accA+accB)/(psA+psB).
__global__ __launch_bounds__(256) void k_comb(const float* __restrict__ part,
                                              f16* __restrict__ qkv,
                                              int nm, int itbase, int Q) {
    int idxp = blockIdx.x;
    int m = idxp % nm;
    int bn = idxp / nm;
    int b = bn >> 3, n = bn & 7;
    int i0 = (m + itbase) * 64;
    int row = threadIdx.x >> 2, dp = (threadIdx.x & 3) * 16;
    if (i0 + row >= Q) return;
    const float* A  = part + (size_t)idxp * 8320;
    const float* Bp = A + 4160;
    float inv = 1.f / (A[4096 + row] + Bp[4096 + row]);
    f16* op = qkv + ((size_t)(i0 + row) * B_ + b) * 1536 + n * 64 + dp;
    #pragma unroll
    for (int k = 0; k < 16; k += 4) {
        float4 a  = *(const float4*)(A  + row * 64 + dp + k);
        float4 bb = *(const float4*)(Bp + row * 64 + dp + k);
        op[k + 0] = (f16)((a.x + bb.x) * inv);
        op[k + 1] = (f16)((a.y + bb.y) * inv);
        op[k + 2] = (f16)((a.z + bb.z) * inv);
        op[k + 3] = (f16)((a.w + bb.w) * inv);
    }
}

// ---------------------------------------------------------------------------
extern "C" void kernel_launch(void* const* d_in, const int* in_sizes, int n_in,
                              void* d_out, int out_size, void* d_ws, size_t ws_size,
                              hipStream_t stream) {
    const int*   data     = (const int*)  d_in[0];
    const float* word_emb = (const float*)d_in[2];
    const float* rwb      = (const float*)d_in[3];
    const float* rrb      = (const float*)d_in[4];
    const float* nullg    = (const float*)d_in[5];
    const float* dg       = (const float*)d_in[6];
    const float* db       = (const float*)d_in[7];
    const float* qkv_w    = (const float*)d_in[8];
    const float* rk_w     = (const float*)d_in[9];
    const float* o_w      = (const float*)d_in[10];
    const float* ln1g     = (const float*)d_in[11];
    const float* ln1b     = (const float*)d_in[12];
    const float* w1       = (const float*)d_in[13];
    const float* b1       = (const float*)d_in[14];
    const float* w2       = (const float*)d_in[15];
    const float* b2       = (const float*)d_in[16];
    const float* ln2g     = (const float*)d_in[17];
    const float* ln2b     = (const float*)d_in[18];
    const float* fw       = (const float*)d_in[19];
    const float* fb       = (const float*)d_in[20];
    float* out = (float*)d_out;
    float* ws  = (float*)d_ws;

    float* x    = ws;                          // 2097152 f
    float* tmp  = x + 2097152;                 // 2097152 f (attn partials / f16 tmp)
    float* xs   = tmp + 2097152;               // 589824 f
    f16* xh     = (f16*)(xs + 589824);         // 2097152 h
    f16* xsh    = xh + 2097152;                // 589824 h
    f16* r1h    = xsh + 589824;                // 524288 h
    f16* r2h    = r1h + 524288;                // 163840 h
    f16* rkall  = r2h + 163840;                // 2623488 h
    f16* bigh   = rkall + 2623488;             // 8388608 h
    f16* qkv_wh = bigh + 8388608;              // 6291456 h
    f16* rk_wh  = qkv_wh + 6291456;            // 2097152 h
    f16* o_wh   = rk_wh + 2097152;             // 2097152 h
    f16* w1h    = o_wh + 2097152;              // 8388608 h
    f16* w2h    = w1h + 8388608;               // 8388608 h
    f16* fwh    = w2h + 8388608;               // 131072 h
    f16* tmph   = (f16*)tmp;                   // alias: o/w2 f16 output

    auto conv = [&](const float* s, f16* d, int n) {
        int blocks = min(2048, (n + 1023) / 1024);
        k_f2h<<<blocks, 256, 0, stream>>>(s, d, n);
    };
    conv(qkv_w, qkv_wh, L_ * 1536 * 512);
    conv(rk_w,  rk_wh,  L_ * 512 * 512);
    conv(o_w,   o_wh,   L_ * 512 * 512);
    conv(w1,    w1h,    L_ * 2048 * 512);
    conv(w2,    w2h,    L_ * 512 * 2048);
    conv(fw,    fwh,    256 * 512);

    auto gemm = [&](const f16* Xp, int lda, const f16* Wp, const float* bp,
                    void* Yp, int M, int N, int K, int out16, int act) {
        int b64_128 = (N % 128 == 0) ? ((M + 63) / 64) * (N / 128) : 0;
        if (b64_128 >= 768) {
            dim3 g((M + 63) / 64, N / 128);
            if (out16) {
                if (act) k_gemm<64, 128, 1, 1><<<g, 256, 0, stream>>>(Xp, lda, Wp, bp, Yp, M, N, K);
                else     k_gemm<64, 128, 1, 0><<<g, 256, 0, stream>>>(Xp, lda, Wp, bp, Yp, M, N, K);
            } else      k_gemm<64, 128, 0, 0><<<g, 256, 0, stream>>>(Xp, lda, Wp, bp, Yp, M, N, K);
            return;
        }
        int b64_64 = ((M + 63) / 64) * (N / 64);
        if (b64_64 >= 768) {
            dim3 g((M + 63) / 64, N / 64);
            if (out16) {
                if (act) k_gemm<64, 64, 1, 1><<<g, 256, 0, stream>>>(Xp, lda, Wp, bp, Yp, M, N, K);
                else     k_gemm<64, 64, 1, 0><<<g, 256, 0, stream>>>(Xp, lda, Wp, bp, Yp, M, N, K);
            } else      k_gemm<64, 64, 0, 0><<<g, 256, 0, stream>>>(Xp, lda, Wp, bp, Yp, M, N, K);
            return;
        }
        dim3 g((M + 31) / 32, N / 64);
        if (out16) {
            if (act) k_gemm<32, 64, 1, 1><<<g, 256, 0, stream>>>(Xp, lda, Wp, bp, Yp, M, N, K);
            else     k_gemm<32, 64, 1, 0><<<g, 256, 0, stream>>>(Xp, lda, Wp, bp, Yp, M, N, K);
        } else      k_gemm<32, 64, 0, 0><<<g, 256, 0, stream>>>(Xp, lda, Wp, bp, Yp, M, N, K);
    };

    k_embed<<<8192, 256, 0, stream>>>(data, word_emb, x, xh);
    k_posemb<<<1024, 256, 0, stream>>>(r1h, 1024);
    k_posemb<<<257, 256, 0, stream>>>(r2h, 257);

    // batched RK precompute (r is layer-invariant)
    gemm(r1h, 512, rk_wh,                nullptr, rkall,           1024, 1024, 512, 1, 0);
    gemm(r1h, 512, rk_wh + 6 * 262144,   nullptr, rkall + 1048576, 1024, 1024, 512, 1, 0);
    gemm(r2h, 512, rk_wh + 2 * 262144,   nullptr, rkall + 2097152,  257, 2048, 512, 1, 0);

    auto stage = [&](float* xb, f16* xbh, int Q, int lo, int hi) {
        const int M = Q * B_;
        dim3 gA = (Q == 1024) ? dim3(24, 32) : dim3(8, 32);
        dim3 gL((M + 3) / 4);
        for (int i = lo; i < hi; ++i) {
            const f16* rkp; int ldr;
            if (i < 2)       { rkp = rkall + i * 512;                 ldr = 1024; }
            else if (i >= 6) { rkp = rkall + 1048576 + (i - 6) * 512; ldr = 1024; }
            else             { rkp = rkall + 2097152 + (i - 2) * 512; ldr = 2048; }
            gemm(xbh, 512, qkv_wh + (size_t)i * 786432, nullptr, bigh, M, 1536, 512, 1, 0);
            k_attn<<<gA, 256, 0, stream>>>(bigh, rkp, ldr, rwb, rrb, Q, tmp);
            if (Q == 1024) k_comb<<<256, 256, 0, stream>>>(tmp, bigh, 8, 8, 1024);
            else           k_comb<<<96, 256, 0, stream>>>(tmp, bigh, 3, 2, 257);
            gemm(bigh, 1536, o_wh + (size_t)i * 262144, nullptr, tmph, M, 512, 512, 1, 0);
            k_ln<<<gL, 256, 0, stream>>>(xb, tmph, ln1g + (size_t)i * 512, ln1b + (size_t)i * 512, xbh, M);
            gemm(xbh, 512, w1h + (size_t)i * 1048576, b1 + (size_t)i * 2048, bigh, M, 2048, 512, 1, 1);
            gemm(bigh, 2048, w2h + (size_t)i * 1048576, b2 + (size_t)i * 512, tmph, M, 512, 2048, 1, 0);
            k_ln<<<gL, 256, 0, stream>>>(xb, tmph, ln2g + (size_t)i * 512, ln2b + (size_t)i * 512, xbh, M);
        }
    };

    stage(x, xh, 1024, 0, 2);                                    // pre
    k_downln<<<257, 256, 0, stream>>>(x, nullg, dg, db, xs, xsh);
    stage(xs, xsh, S_ + 1, 2, 6);                                // shortened
    k_up<<<8192, 256, 0, stream>>>(x, xs, xh);                   // upsample + residual
    stage(x, xh, 1024, 6, 8);                                    // post
    gemm(xh, 512, fwh, fb, out, T_ * B_, V_, 512, 0, 0);         // logits
}

// Round 11
// 778.304 us; speedup vs baseline: 1.1125x; 1.1125x over previous
//
#include <hip/hip_runtime.h>
#include <math.h>

#define T_  1024
#define B_  4
#define D_  512
#define H_  8
#define DH_ 64
#define DI_ 2048
#define V_  256
#define L_  8
#define S_  256   // segments

typedef _Float16 f16;
typedef f16   f16x8 __attribute__((ext_vector_type(8)));
typedef f16   f16x4 __attribute__((ext_vector_type(4)));
typedef float f32x4 __attribute__((ext_vector_type(4)));

__device__ __forceinline__ void gload16(const void* g, void* l) {
    __builtin_amdgcn_global_load_lds(
        (const __attribute__((address_space(1))) void*)g,
        (__attribute__((address_space(3))) void*)l, 16, 0, 0);
}

// Q=1024 task table: 24 tasks/(b,n), breadth-first CU triples sum to 17.
__constant__ int cIT[24] = {15,15,14,13,12,11,10, 9,  8, 7,14, 6,13, 5,12, 4,  8, 0, 9, 1,10, 2,11, 3};
__constant__ int cT0[24] = { 0, 8, 0, 0, 0, 0, 0, 0,  0, 0, 8, 0, 8, 0, 8, 0,  8, 0, 8, 0, 8, 0, 8, 0};
__constant__ int cT1[24] = { 8,16, 8, 8, 8, 8, 8, 8,  8, 8,15, 7,14, 6,13, 5,  9, 1,10, 2,11, 3,12, 4};
// Q=257 task table: 8 tasks/(b,n) = 256 blocks = 1/CU.
__constant__ int cIT2[8] = {4,4,3,3,2,2,1,0};
__constant__ int cT02[8] = {0,3,0,2,0,2,0,0};
__constant__ int cT12[8] = {3,5,2,4,2,3,2,1};

// ---------------------------------------------------------------------------
// One-launch fp32->fp16 weight conversion (6 tensors).
__global__ __launch_bounds__(256) void k_f2hall(
        const float* s0, f16* d0, int n0, const float* s1, f16* d1, int n1,
        const float* s2, f16* d2, int n2, const float* s3, f16* d3, int n3,
        const float* s4, f16* d4, int n4, const float* s5, f16* d5, int n5) {
    int start = (blockIdx.x * 256 + threadIdx.x) * 4;
    int stride = gridDim.x * 1024;
    const float* ss[6] = {s0, s1, s2, s3, s4, s5};
    f16* dd[6] = {d0, d1, d2, d3, d4, d5};
    int nn[6] = {n0, n1, n2, n3, n4, n5};
    for (int seg = 0; seg < 6; ++seg) {
        const float* s = ss[seg]; f16* d = dd[seg]; int n = nn[seg];
        for (int i = start; i < n; i += stride) {
            float4 v = *(const float4*)(s + i);
            f16x4 h = {(f16)v.x, (f16)v.y, (f16)v.z, (f16)v.w};
            *(f16x4*)(d + i) = h;
        }
    }
}

// ---------------------------------------------------------------------------
// Embedding -> f16 residual stream
__global__ __launch_bounds__(256) void k_embed(const int* __restrict__ data,
                                               const float* __restrict__ emb,
                                               f16* __restrict__ xh) {
    int i4 = (blockIdx.x * 256 + threadIdx.x) * 4;
    if (i4 >= T_ * B_ * D_) return;
    int d  = i4 & (D_ - 1);
    int tb = i4 >> 9;
    float4 v = *(const float4*)(emb + (size_t)data[tb] * D_ + d);
    f16x4 h = {(f16)v.x, (f16)v.y, (f16)v.z, (f16)v.w};
    *(f16x4*)(xh + i4) = h;
}

// ---------------------------------------------------------------------------
__global__ __launch_bounds__(256) void k_posemb(f16* __restrict__ r, int qlen) {
    int p = blockIdx.x;
    int k = threadIdx.x;
    float pos = (float)(qlen - 1 - p);
    float inv = exp2f((float)k * -0.05190512648f);   // 10000^(-k/256)
    float ang = pos * inv;
    r[(size_t)p * D_ + k]       = (f16)sinf(ang);
    r[(size_t)p * D_ + 256 + k] = (f16)cosf(ang);
}

// ---------------------------------------------------------------------------
// MFMA fp16 GEMM, m97 1-phase structure (R9-proven) + XCD-chunked swizzle +
// optional split-K over blockIdx.z (each z writes its own f16 partial slab;
// bias applied only by z==0; never used with ACT). X has row stride lda.
template<int BM, int BN, int OUT16, int ACT>
__global__ __launch_bounds__(256) void k_gemm(const f16* __restrict__ X, int lda,
                                              const f16* __restrict__ W,
                                              const float* __restrict__ bias,
                                              void* __restrict__ Yv,
                                              int M, int N, int K) {
    __shared__ f16 As[BM * 64];
    __shared__ f16 Bs[BN * 64];
    const int tid = threadIdx.x, w = tid >> 6, lane = tid & 63;
    const int l16 = lane & 15, lg = lane >> 4;
    int nwg = gridDim.x * gridDim.y;
    int bid = blockIdx.y * gridDim.x + blockIdx.x;
    if ((nwg & 7) == 0) bid = (bid & 7) * (nwg >> 3) + (bid >> 3);   // XCD chunked
    const int bm = (bid % gridDim.x) * BM, bn = (bid / gridDim.x) * BN;
    const int Kz = K / gridDim.z;
    const int kbeg = blockIdx.z * Kz, kend = kbeg + Kz;
    const size_t zofs = (size_t)blockIdx.z * M * N;
    const int lrow = lane >> 3, lcol = (lane & 7) * 8;
    constexpr int AI = BM / 32;
    constexpr int BI = BN / 32;
    constexpr int MI = (BN == 128) ? 4 : BM / 32;
    constexpr int NJ = 2;
    const int rbase = (BN == 128) ? 0 : (w >> 1) * (BM / 2);
    const int cbase = (BN == 128) ? w * 32 : (w & 1) * 32;
    const f32x4 z4 = {0.f, 0.f, 0.f, 0.f};
    f32x4 acc[MI][NJ];
    #pragma unroll
    for (int i = 0; i < MI; ++i)
        #pragma unroll
        for (int j = 0; j < NJ; ++j) acc[i][j] = z4;

    for (int k0 = kbeg; k0 < kend; k0 += 64) {
        __syncthreads();
        #pragma unroll
        for (int u = 0; u < AI; ++u) {
            int rb = w * (BM / 4) + u * 8;
            gload16(X + (size_t)(bm + rb + lrow) * lda + k0 + lcol, &As[rb * 64]);
        }
        #pragma unroll
        for (int u = 0; u < BI; ++u) {
            int rb = w * (BN / 4) + u * 8;
            gload16(W + (size_t)(bn + rb + lrow) * K + k0 + lcol, &Bs[rb * 64]);
        }
        __syncthreads();
        __builtin_amdgcn_s_setprio(1);
        #pragma unroll
        for (int h = 0; h < 2; ++h) {
            f16x8 af[MI], bf[NJ];
            #pragma unroll
            for (int i = 0; i < MI; ++i)
                af[i] = *(const f16x8*)&As[(rbase + i * 16 + l16) * 64 + h * 32 + lg * 8];
            #pragma unroll
            for (int j = 0; j < NJ; ++j)
                bf[j] = *(const f16x8*)&Bs[(cbase + j * 16 + l16) * 64 + h * 32 + lg * 8];
            #pragma unroll
            for (int i = 0; i < MI; ++i)
                #pragma unroll
                for (int j = 0; j < NJ; ++j)
                    acc[i][j] = __builtin_amdgcn_mfma_f32_16x16x32_f16(af[i], bf[j], acc[i][j], 0, 0, 0);
        }
        __builtin_amdgcn_s_setprio(0);
    }
    const bool dob = bias && (blockIdx.z == 0);
    #pragma unroll
    for (int i = 0; i < MI; ++i) {
        #pragma unroll
        for (int r = 0; r < 4; ++r) {
            int row = bm + rbase + i * 16 + lg * 4 + r;
            if (row >= M) continue;
            int colb = bn + cbase + l16;
            #pragma unroll
            for (int j = 0; j < NJ; ++j) {
                float v = acc[i][j][r];
                if (dob) v += bias[colb + j * 16];
                if (ACT) v = fmaxf(v, 0.f);
                if (OUT16) ((f16*)Yv)[zofs + (size_t)row * N + colb + j * 16] = (f16)v;
                else       ((float*)Yv)[(size_t)row * N + colb + j * 16] = v;
            }
        }
    }
}

// ---------------------------------------------------------------------------
// LayerNorm over f16 residual stream: xh = LN(xh + sum_s add[s]) * g + b.
// One WAVE per row, 4 rows/block. nadd f16 add-slabs of stride astr.
__global__ __launch_bounds__(256) void k_ln(f16* __restrict__ xh,
                                            const f16* __restrict__ add,
                                            int nadd, int astr,
                                            const float* __restrict__ g,
                                            const float* __restrict__ b,
                                            int rows) {
    int row = blockIdx.x * 4 + (threadIdx.x >> 6);
    if (row >= rows) return;
    int lane = threadIdx.x & 63;
    f16* xr = xh + (size_t)row * D_ + lane * 8;
    float v[8];
    {
        f16x8 a = *(const f16x8*)xr;
        #pragma unroll
        for (int u = 0; u < 8; ++u) v[u] = (float)a[u];
    }
    const f16* ap = add + (size_t)row * D_ + lane * 8;
    for (int s = 0; s < nadd; ++s) {
        f16x8 a = *(const f16x8*)(ap + (size_t)s * astr);
        #pragma unroll
        for (int u = 0; u < 8; ++u) v[u] += (float)a[u];
    }
    float sm = 0.f, sq = 0.f;
    #pragma unroll
    for (int u = 0; u < 8; ++u) { sm += v[u]; sq += v[u] * v[u]; }
    #pragma unroll
    for (int off = 1; off < 64; off <<= 1) {
        sm += __shfl_xor(sm, off, 64);
        sq += __shfl_xor(sq, off, 64);
    }
    float mean = sm * (1.f / (float)D_);
    float var  = sq * (1.f / (float)D_) - mean * mean;
    float rs   = rsqrtf(var + 1e-5f);
    const float* gp = g + lane * 8;
    const float* bp = b + lane * 8;
    float4 g0 = *(const float4*)gp, g1 = *(const float4*)(gp + 4);
    float4 b0 = *(const float4*)bp, b1 = *(const float4*)(bp + 4);
    float gg[8] = {g0.x, g0.y, g0.z, g0.w, g1.x, g1.y, g1.z, g1.w};
    float bb[8] = {b0.x, b0.y, b0.z, b0.w, b1.x, b1.y, b1.z, b1.w};
    f16x8 hv;
    #pragma unroll
    for (int u = 0; u < 8; ++u) hv[u] = (f16)((v[u] - mean) * rs * gg[u] + bb[u]);
    *(f16x8*)xr = hv;
}

// ---------------------------------------------------------------------------
// Fused downsample (mean-pool + null row) + LayerNorm over f16 stream.
__global__ __launch_bounds__(256) void k_downln(const f16* __restrict__ xh,
                                                const float* __restrict__ nullg,
                                                const float* __restrict__ g,
                                                const float* __restrict__ bi,
                                                f16* __restrict__ xsh) {
    int row = blockIdx.x * 4 + (threadIdx.x >> 6);
    if (row >= (S_ + 1) * B_) return;
    int lane = threadIdx.x & 63;
    int s = row >> 2, b = row & 3;
    float v[8];
    if (s == 0) {
        const float* np = nullg + lane * 8;
        float4 a0 = *(const float4*)np, a1 = *(const float4*)(np + 4);
        v[0] = a0.x; v[1] = a0.y; v[2] = a0.z; v[3] = a0.w;
        v[4] = a1.x; v[5] = a1.y; v[6] = a1.z; v[7] = a1.w;
    } else {
        int t0 = (s - 1) * 4;
        #pragma unroll
        for (int u = 0; u < 8; ++u) v[u] = 0.f;
        #pragma unroll
        for (int k = 0; k < 4; ++k) {
            f16x8 a = *(const f16x8*)(xh + ((size_t)(t0 + k) * B_ + b) * D_ + lane * 8);
            #pragma unroll
            for (int u = 0; u < 8; ++u) v[u] += (float)a[u];
        }
        #pragma unroll
        for (int u = 0; u < 8; ++u) v[u] *= 0.25f;
    }
    float sm = 0.f, sq = 0.f;
    #pragma unroll
    for (int u = 0; u < 8; ++u) { sm += v[u]; sq += v[u] * v[u]; }
    #pragma unroll
    for (int off = 1; off < 64; off <<= 1) {
        sm += __shfl_xor(sm, off, 64);
        sq += __shfl_xor(sq, off, 64);
    }
    float mean = sm * (1.f / (float)D_);
    float var  = sq * (1.f / (float)D_) - mean * mean;
    float rs   = rsqrtf(var + 1e-5f);
    f16x8 hv;
    #pragma unroll
    for (int u = 0; u < 8; ++u)
        hv[u] = (f16)((v[u] - mean) * rs * g[lane * 8 + u] + bi[lane * 8 + u]);
    *(f16x8*)(xsh + (size_t)row * D_ + lane * 8) = hv;
}

// Upsample + residual on f16 stream: xh[t,b,:] += xsh[(t+1)/4, b, :]
__global__ __launch_bounds__(256) void k_up(f16* __restrict__ xh,
                                            const f16* __restrict__ xsh) {
    int i8 = (blockIdx.x * 256 + threadIdx.x) * 8;
    if (i8 >= T_ * B_ * D_) return;
    int d  = i8 & (D_ - 1);
    int tb = i8 >> 9;
    int t = tb >> 2, b = tb & 3;
    int seg = (t + 1) >> 2;
    f16x8 a = *(const f16x8*)(xh + i8);
    f16x8 u2 = *(const f16x8*)(xsh + ((size_t)seg * B_ + b) * D_ + d);
    f16x8 o;
    #pragma unroll
    for (int u = 0; u < 8; ++u) o[u] = (f16)((float)a[u] + (float)u2[u]);
    *(f16x8*)(xh + i8) = o;
}

// ---------------------------------------------------------------------------
// MFMA flash attention (R9-proven v6): balanced task tables (Q=1024: 24 tasks,
// CU-sum=17; Q=257: 8 tasks = 1/CU), deferred softmax, swizzled LDS, circular
// RK window, 1-deep prefetch, XCD-local mapping. Split partials combine by
// plain addition (k_comb).
__global__ __launch_bounds__(256) void k_attn(f16* __restrict__ qkv,
                                              const f16* __restrict__ rkb,
                                              int ldr,
                                              const float* __restrict__ rwb,
                                              const float* __restrict__ rrb,
                                              int Q, float* __restrict__ part) {
    __shared__ f16 RKs[192 * 64];
    __shared__ f16 Ks[64 * 64];
    __shared__ f16 Vt[64 * 72];
    __shared__ f16 Pl[4][16 * 72];
    f16* Qw = RKs;
    f16* Qr = RKs + 4096;

    int it, t0, t1, b, n;
    bool partial;
    int idxp;
    {
        int p = blockIdx.y * gridDim.x + blockIdx.x;
        int xcd = p & 7, qq = p >> 3;
        b = xcd >> 1;
        n = (xcd & 1) * 4 + (qq & 3);
        int slot = qq >> 2;
        if (Q == 1024) {
            it = cIT[slot]; t0 = cT0[slot]; t1 = cT1[slot];
            partial = (it >= 8);
            idxp = (b * 8 + n) * 8 + (it - 8);
        } else {           // Q == 257, grid (8,32)
            it = cIT2[slot]; t0 = cT02[slot]; t1 = cT12[slot];
            partial = (it >= 2);
            idxp = (b * 8 + n) * 3 + (it - 2);
        }
    }
    const int i0 = it * 64;
    const int tid = threadIdx.x, w = tid >> 6, lane = tid & 63;
    const int l16 = lane & 15, lg = lane >> 4;
    const int xsw = (l16 & 7) << 3;
    const int gr8 = lane >> 3;
    const int gsl = ((lane & 7) ^ gr8) * 8;
    const int vjj = tid >> 2, vdb = (tid & 3) * 16;
    const int wb = 48 - w * 16;
    const f32x4 z4 = {0.f, 0.f, 0.f, 0.f};

    {   // stage Q (+biases) into RK alias, swizzled
        int row = tid >> 2, dq = (tid & 3) * 16;
        const f16* qp = qkv + ((size_t)(i0 + row) * B_ + b) * 1536 + n * 64 + dq;
        f16x8 q0 = *(const f16x8*)qp, q1 = *(const f16x8*)(qp + 8);
        int rsw = (row & 7) << 3;
        #pragma unroll
        for (int u = 0; u < 8; ++u) {
            float qa = (float)q0[u], qb2 = (float)q1[u];
            Qw[row * 64 + ((dq + u) ^ rsw)]     = (f16)(qa + rwb[n * 64 + dq + u]);
            Qw[row * 64 + ((dq + 8 + u) ^ rsw)] = (f16)(qb2 + rwb[n * 64 + dq + 8 + u]);
            Qr[row * 64 + ((dq + u) ^ rsw)]     = (f16)(qa + rrb[n * 64 + dq + u]);
            Qr[row * 64 + ((dq + 8 + u) ^ rsw)] = (f16)(qb2 + rrb[n * 64 + dq + 8 + u]);
        }
    }
    __syncthreads();
    f16x8 aqw[2], aqr[2];
    #pragma unroll
    for (int h = 0; h < 2; ++h) {
        aqw[h] = *(const f16x8*)&Qw[(w * 16 + l16) * 64 + ((h * 32 + lg * 8) ^ xsw)];
        aqr[h] = *(const f16x8*)&Qr[(w * 16 + l16) * 64 + ((h * 32 + lg * 8) ^ xsw)];
    }
    __syncthreads();

    const long long pb = (long long)Q - 64 - i0;
    #pragma unroll
    for (int u = 0; u < 4; ++u) {
        int rb = w * 32 + u * 8;
        long long p = pb + t0 * 64 + rb + gr8;
        gload16(rkb + p * ldr + n * 64 + gsl, &RKs[rb * 64]);
    }
    #pragma unroll
    for (int u = 0; u < 2; ++u) {
        int rb = w * 16 + u * 8;
        gload16(qkv + ((size_t)(t0 * 64 + rb + gr8) * B_ + b) * 1536 + 512 + n * 64 + gsl,
                &Ks[rb * 64]);
    }
    f16x8 vr0, vr1;
    {
        const f16* vp = qkv + ((size_t)(t0 * 64 + vjj) * B_ + b) * 1536 + 1024 + n * 64 + vdb;
        vr0 = *(const f16x8*)vp; vr1 = *(const f16x8*)(vp + 8);
    }

    f32x4 acc[4]; acc[0] = z4; acc[1] = z4; acc[2] = z4; acc[3] = z4;
    float psum[4] = {0.f, 0.f, 0.f, 0.f};
    int base = 0;

    for (int t = t0; t < t1; ++t) {
        const int j0 = t * 64;
        __syncthreads();   // A
        #pragma unroll
        for (int u = 0; u < 8; ++u) {
            Vt[(vdb + u) * 72 + (vjj ^ ((u & 7) << 3))]     = vr0[u];
            Vt[(vdb + 8 + u) * 72 + (vjj ^ ((u & 7) << 3))] = vr1[u];
        }
        if (t + 1 < t1) {
            int sb = base + 128; if (sb >= 192) sb -= 192;
            #pragma unroll
            for (int u = 0; u < 2; ++u) {
                int rb = w * 16 + u * 8;
                long long p = pb + j0 + 128 + rb + gr8;
                gload16(rkb + p * ldr + n * 64 + gsl, &RKs[(sb + rb) * 64]);
            }
        }
        f32x4 s1[4]; s1[0] = z4; s1[1] = z4; s1[2] = z4; s1[3] = z4;
        __builtin_amdgcn_s_setprio(1);
        #pragma unroll
        for (int f = 0; f < 4; ++f)
            #pragma unroll
            for (int h = 0; h < 2; ++h) {
                f16x8 bv = *(const f16x8*)&Ks[(f * 16 + l16) * 64 + ((h * 32 + lg * 8) ^ xsw)];
                s1[f] = __builtin_amdgcn_mfma_f32_16x16x32_f16(aqw[h], bv, s1[f], 0, 0, 0);
            }
        __builtin_amdgcn_s_setprio(0);
        if (t + 1 < t1) {
            const f16* vp = qkv + ((size_t)(j0 + 64 + vjj) * B_ + b) * 1536 + 1024 + n * 64 + vdb;
            vr0 = *(const f16x8*)vp; vr1 = *(const f16x8*)(vp + 8);
        }
        f32x4 s2[5]; s2[0] = z4; s2[1] = z4; s2[2] = z4; s2[3] = z4; s2[4] = z4;
        __builtin_amdgcn_s_setprio(1);
        #pragma unroll
        for (int f = 0; f < 5; ++f) {
            int slot = base + wb + f * 16 + l16; if (slot >= 192) slot -= 192;
            #pragma unroll
            for (int h = 0; h < 2; ++h) {
                f16x8 bv = *(const f16x8*)&RKs[slot * 64 + ((h * 32 + lg * 8) ^ xsw)];
                s2[f] = __builtin_amdgcn_mfma_f32_16x16x32_f16(aqr[h], bv, s2[f], 0, 0, 0);
            }
        }
        __builtin_amdgcn_s_setprio(0);
        // deferred softmax: p = exp(s*scale); lane-local row-sum
        #pragma unroll
        for (int r = 0; r < 4; ++r) {
            const int q = lg * 4 + r;
            const int iq = i0 + w * 16 + q;
            const int src = (lane & 48) | ((l16 + 15 - q) & 15);
            float g0 = __shfl(s2[0][r], src, 64);
            float g1 = __shfl(s2[1][r], src, 64);
            float g2 = __shfl(s2[2][r], src, 64);
            float g3 = __shfl(s2[3][r], src, 64);
            float g4 = __shfl(s2[4][r], src, 64);
            const bool hi = l16 > q;
            float sv[4];
            sv[0] = (s1[0][r] + (hi ? g1 : g0)) * 0.125f;
            sv[1] = (s1[1][r] + (hi ? g2 : g1)) * 0.125f;
            sv[2] = (s1[2][r] + (hi ? g3 : g2)) * 0.125f;
            sv[3] = (s1[3][r] + (hi ? g4 : g3)) * 0.125f;
            #pragma unroll
            for (int h = 0; h < 4; ++h) {
                int j = j0 + h * 16 + l16;
                if (j > iq || j >= Q) sv[h] = -1e30f;
            }
            float p0 = __expf(sv[0]), p1 = __expf(sv[1]);
            float p2 = __expf(sv[2]), p3 = __expf(sv[3]);
            psum[r] += (p0 + p1) + (p2 + p3);
            Pl[w][q * 72 + l16]      = (f16)p0;
            Pl[w][q * 72 + 16 + l16] = (f16)p1;
            Pl[w][q * 72 + 32 + l16] = (f16)p2;
            Pl[w][q * 72 + 48 + l16] = (f16)p3;
        }
        __syncthreads();   // B
        f16x8 pa0 = *(const f16x8*)&Pl[w][l16 * 72 + lg * 8];
        f16x8 pa1 = *(const f16x8*)&Pl[w][l16 * 72 + 32 + lg * 8];
        __builtin_amdgcn_s_setprio(1);
        #pragma unroll
        for (int f = 0; f < 4; ++f) {
            f16x8 bv0 = *(const f16x8*)&Vt[(f * 16 + l16) * 72 + ((lg * 8) ^ xsw)];
            acc[f] = __builtin_amdgcn_mfma_f32_16x16x32_f16(pa0, bv0, acc[f], 0, 0, 0);
            f16x8 bv1 = *(const f16x8*)&Vt[(f * 16 + l16) * 72 + ((32 + lg * 8) ^ xsw)];
            acc[f] = __builtin_amdgcn_mfma_f32_16x16x32_f16(pa1, bv1, acc[f], 0, 0, 0);
        }
        __builtin_amdgcn_s_setprio(0);
        if (t + 1 < t1) {
            #pragma unroll
            for (int u = 0; u < 2; ++u) {
                int rb = w * 16 + u * 8;
                gload16(qkv + ((size_t)(j0 + 64 + rb + gr8) * B_ + b) * 1536 + 512 + n * 64 + gsl,
                        &Ks[rb * 64]);
            }
        }
        base += 64; if (base >= 192) base -= 192;
    }
    if (partial) {
        float* Pp = part + (size_t)idxp * 8320 + (t0 ? 4160 : 0);
        #pragma unroll
        for (int r = 0; r < 4; ++r) {
            float ps = psum[r];
            ps += __shfl_xor(ps, 1, 64);
            ps += __shfl_xor(ps, 2, 64);
            ps += __shfl_xor(ps, 4, 64);
            ps += __shfl_xor(ps, 8, 64);
            int row = w * 16 + lg * 4 + r;
            #pragma unroll
            for (int f = 0; f < 4; ++f)
                Pp[row * 64 + f * 16 + l16] = acc[f][r];
            if (l16 == 0) Pp[4096 + row] = ps;
        }
    } else {
        #pragma unroll
        for (int r = 0; r < 4; ++r) {
            float ps = psum[r];
            ps += __shfl_xor(ps, 1, 64);
            ps += __shfl_xor(ps, 2, 64);
            ps += __shfl_xor(ps, 4, 64);
            ps += __shfl_xor(ps, 8, 64);
            int i = i0 + w * 16 + lg * 4 + r;
            if (i < Q) {
                float inv = 1.f / ps;
                f16* op = qkv + ((size_t)i * B_ + b) * 1536 + n * 64;
                #pragma unroll
                for (int f = 0; f < 4; ++f)
                    op[f * 16 + l16] = (f16)(acc[f][r] * inv);
            }
        }
    }
}

// ---------------------------------------------------------------------------
// Combine split-attention partials: out = (accA+accB)/(psA+psB).
__global__ __launch_bounds__(256) void k_comb(const float* __restrict__ part,
                                              f16* __restrict__ qkv,
                                              int nm, int itbase, int Q) {
    int idxp = blockIdx.x;
    int m = idxp % nm;
    int bn = idxp / nm;
    int b = bn >> 3, n = bn & 7;
    int i0 = (m + itbase) * 64;
    int row = threadIdx.x >> 2, dp = (threadIdx.x & 3) * 16;
    if (i0 + row >= Q) return;
    const float* A  = part + (size_t)idxp * 8320;
    const float* Bp = A + 4160;
    float inv = 1.f / (A[4096 + row] + Bp[4096 + row]);
    f16* op = qkv + ((size_t)(i0 + row) * B_ + b) * 1536 + n * 64 + dp;
    #pragma unroll
    for (int k = 0; k < 16; k += 4) {
        float4 a  = *(const float4*)(A  + row * 64 + dp + k);
        float4 bb = *(const float4*)(Bp + row * 64 + dp + k);
        op[k + 0] = (f16)((a.x + bb.x) * inv);
        op[k + 1] = (f16)((a.y + bb.y) * inv);
        op[k + 2] = (f16)((a.z + bb.z) * inv);
        op[k + 3] = (f16)((a.w + bb.w) * inv);
    }
}

// ---------------------------------------------------------------------------
extern "C" void kernel_launch(void* const* d_in, const int* in_sizes, int n_in,
                              void* d_out, int out_size, void* d_ws, size_t ws_size,
                              hipStream_t stream) {
    const int*   data     = (const int*)  d_in[0];
    const float* word_emb = (const float*)d_in[2];
    const float* rwb      = (const float*)d_in[3];
    const float* rrb      = (const float*)d_in[4];
    const float* nullg    = (const float*)d_in[5];
    const float* dg       = (const float*)d_in[6];
    const float* db       = (const float*)d_in[7];
    const float* qkv_w    = (const float*)d_in[8];
    const float* rk_w     = (const float*)d_in[9];
    const float* o_w      = (const float*)d_in[10];
    const float* ln1g     = (const float*)d_in[11];
    const float* ln1b     = (const float*)d_in[12];
    const float* w1       = (const float*)d_in[13];
    const float* b1       = (const float*)d_in[14];
    const float* w2       = (const float*)d_in[15];
    const float* b2       = (const float*)d_in[16];
    const float* ln2g     = (const float*)d_in[17];
    const float* ln2b     = (const float*)d_in[18];
    const float* fw       = (const float*)d_in[19];
    const float* fb       = (const float*)d_in[20];
    float* out = (float*)d_out;
    float* ws  = (float*)d_ws;

    // workspace (~92 MB), f16-only residual stream.
    // ov: overlay — attn fp32 partials & GEMM f16 tmp/partials (disjoint lifetimes)
    float* ov   = ws;                          // 2129920 f (8.52 MB)
    f16* tmph   = (f16*)ov;                    // alias (capacity 4259840 h)
    f16* xh     = (f16*)(ov + 2129920);        // 2097152 h
    f16* xsh    = xh + 2097152;                // 589824 h
    f16* r1h    = xsh + 589824;                // 524288 h
    f16* r2h    = r1h + 524288;                // 163840 h
    f16* rkall  = r2h + 163840;                // 2623488 h
    f16* bigh   = rkall + 2623488;             // 8388608 h
    f16* qkv_wh = bigh + 8388608;              // 6291456 h
    f16* rk_wh  = qkv_wh + 6291456;            // 2097152 h
    f16* o_wh   = rk_wh + 2097152;             // 2097152 h
    f16* w1h    = o_wh + 2097152;              // 8388608 h
    f16* w2h    = w1h + 8388608;               // 8388608 h
    f16* fwh    = w2h + 8388608;               // 131072 h

    k_f2hall<<<2048, 256, 0, stream>>>(
        qkv_w, qkv_wh, L_ * 1536 * 512,
        rk_w,  rk_wh,  L_ * 512 * 512,
        o_w,   o_wh,   L_ * 512 * 512,
        w1,    w1h,    L_ * 2048 * 512,
        w2,    w2h,    L_ * 512 * 2048,
        fw,    fwh,    256 * 512);

    auto gemm = [&](const f16* Xp, int lda, const f16* Wp, const float* bp,
                    void* Yp, int M, int N, int K, int out16, int act, int splitk) {
        if (splitk > 1) {                       // forced 32x64 split-K path
            dim3 g((M + 31) / 32, N / 64, splitk);
            k_gemm<32, 64, 1, 0><<<g, 256, 0, stream>>>(Xp, lda, Wp, bp, Yp, M, N, K);
            return;
        }
        int b64_128 = (N % 128 == 0) ? ((M + 63) / 64) * (N / 128) : 0;
        if (b64_128 >= 768) {
            dim3 g((M + 63) / 64, N / 128);
            if (out16) {
                if (act) k_gemm<64, 128, 1, 1><<<g, 256, 0, stream>>>(Xp, lda, Wp, bp, Yp, M, N, K);
                else     k_gemm<64, 128, 1, 0><<<g, 256, 0, stream>>>(Xp, lda, Wp, bp, Yp, M, N, K);
            } else      k_gemm<64, 128, 0, 0><<<g, 256, 0, stream>>>(Xp, lda, Wp, bp, Yp, M, N, K);
            return;
        }
        int b64_64 = ((M + 63) / 64) * (N / 64);
        if (b64_64 >= 768) {
            dim3 g((M + 63) / 64, N / 64);
            if (out16) {
                if (act) k_gemm<64, 64, 1, 1><<<g, 256, 0, stream>>>(Xp, lda, Wp, bp, Yp, M, N, K);
                else     k_gemm<64, 64, 1, 0><<<g, 256, 0, stream>>>(Xp, lda, Wp, bp, Yp, M, N, K);
            } else      k_gemm<64, 64, 0, 0><<<g, 256, 0, stream>>>(Xp, lda, Wp, bp, Yp, M, N, K);
            return;
        }
        dim3 g((M + 31) / 32, N / 64);
        if (out16) {
            if (act) k_gemm<32, 64, 1, 1><<<g, 256, 0, stream>>>(Xp, lda, Wp, bp, Yp, M, N, K);
            else     k_gemm<32, 64, 1, 0><<<g, 256, 0, stream>>>(Xp, lda, Wp, bp, Yp, M, N, K);
        } else      k_gemm<32, 64, 0, 0><<<g, 256, 0, stream>>>(Xp, lda, Wp, bp, Yp, M, N, K);
    };

    k_embed<<<2048, 256, 0, stream>>>(data, word_emb, xh);
    k_posemb<<<1024, 256, 0, stream>>>(r1h, 1024);
    k_posemb<<<257, 256, 0, stream>>>(r2h, 257);

    // batched RK precompute (r is layer-invariant)
    gemm(r1h, 512, rk_wh,              nullptr, rkall,           1024, 1024, 512, 1, 0, 1);
    gemm(r1h, 512, rk_wh + 6 * 262144, nullptr, rkall + 1048576, 1024, 1024, 512, 1, 0, 1);
    gemm(r2h, 512, rk_wh + 2 * 262144, nullptr, rkall + 2097152,  257, 2048, 512, 1, 0, 1);

    auto stage = [&](f16* xbh, int Q, int lo, int hi) {
        const int M = Q * B_;
        dim3 gA = (Q == 1024) ? dim3(24, 32) : dim3(8, 32);
        dim3 gL((M + 3) / 4);
        const int sk_o  = (Q == 1024) ? 1 : 2;   // split-K for the 264-block GEMMs
        const int sk_w2 = (Q == 1024) ? 1 : 4;
        for (int i = lo; i < hi; ++i) {
            const f16* rkp; int ldr;
            if (i < 2)       { rkp = rkall + i * 512;                 ldr = 1024; }
            else if (i >= 6) { rkp = rkall + 1048576 + (i - 6) * 512; ldr = 1024; }
            else             { rkp = rkall + 2097152 + (i - 2) * 512; ldr = 2048; }
            gemm(xbh, 512, qkv_wh + (size_t)i * 786432, nullptr, bigh, M, 1536, 512, 1, 0, 1);
            k_attn<<<gA, 256, 0, stream>>>(bigh, rkp, ldr, rwb, rrb, Q, ov);
            if (Q == 1024) k_comb<<<256, 256, 0, stream>>>(ov, bigh, 8, 8, 1024);
            else           k_comb<<<96, 256, 0, stream>>>(ov, bigh, 3, 2, 257);
            gemm(bigh, 1536, o_wh + (size_t)i * 262144, nullptr, tmph, M, 512, 512, 1, 0, sk_o);
            k_ln<<<gL, 256, 0, stream>>>(xbh, tmph, sk_o, M * 512,
                                         ln1g + (size_t)i * 512, ln1b + (size_t)i * 512, M);
            gemm(xbh, 512, w1h + (size_t)i * 1048576, b1 + (size_t)i * 2048, bigh, M, 2048, 512, 1, 1, 1);
            gemm(bigh, 2048, w2h + (size_t)i * 1048576, b2 + (size_t)i * 512, tmph, M, 512, 2048, 1, 0, sk_w2);
            k_ln<<<gL, 256, 0, stream>>>(xbh, tmph, sk_w2, M * 512,
                                         ln2g + (size_t)i * 512, ln2b + (size_t)i * 512, M);
        }
    };

    stage(xh, 1024, 0, 2);                                       // pre
    k_downln<<<257, 256, 0, stream>>>(xh, nullg, dg, db, xsh);
    stage(xsh, S_ + 1, 2, 6);                                    // shortened
    k_up<<<1024, 256, 0, stream>>>(xh, xsh);                     // upsample + residual
    stage(xh, 1024, 6, 8);                                       // post
    gemm(xh, 512, fwh, fb, out, T_ * B_, V_, 512, 0, 0, 1);      // logits
}

// Round 12
// 766.251 us; speedup vs baseline: 1.1300x; 1.0157x over previous
//
#include <hip/hip_runtime.h>
#include <math.h>

#define T_  1024
#define B_  4
#define D_  512
#define H_  8
#define DH_ 64
#define DI_ 2048
#define V_  256
#define L_  8
#define S_  256   // segments

typedef _Float16 f16;
typedef f16   f16x8 __attribute__((ext_vector_type(8)));
typedef f16   f16x4 __attribute__((ext_vector_type(4)));
typedef float f32x4 __attribute__((ext_vector_type(4)));

__device__ __forceinline__ void gload16(const void* g, void* l) {
    __builtin_amdgcn_global_load_lds(
        (const __attribute__((address_space(1))) void*)g,
        (__attribute__((address_space(3))) void*)l, 16, 0, 0);
}

// Q=1024 task table: 24 tasks/(b,n), breadth-first CU triples sum to 17.
__constant__ int cIT[24] = {15,15,14,13,12,11,10, 9,  8, 7,14, 6,13, 5,12, 4,  8, 0, 9, 1,10, 2,11, 3};
__constant__ int cT0[24] = { 0, 8, 0, 0, 0, 0, 0, 0,  0, 0, 8, 0, 8, 0, 8, 0,  8, 0, 8, 0, 8, 0, 8, 0};
__constant__ int cT1[24] = { 8,16, 8, 8, 8, 8, 8, 8,  8, 8,15, 7,14, 6,13, 5,  9, 1,10, 2,11, 3,12, 4};
// Q=257 task table: 8 tasks/(b,n) = 256 blocks = 1/CU.
__constant__ int cIT2[8] = {4,4,3,3,2,2,1,0};
__constant__ int cT02[8] = {0,3,0,2,0,2,0,0};
__constant__ int cT12[8] = {3,5,2,4,2,3,2,1};

// ---------------------------------------------------------------------------
// One-launch fp32->fp16 weight conversion, 8 elems/thread (16B stores).
__global__ __launch_bounds__(256) void k_f2hall(
        const float* s0, f16* d0, int n0, const float* s1, f16* d1, int n1,
        const float* s2, f16* d2, int n2, const float* s3, f16* d3, int n3,
        const float* s4, f16* d4, int n4, const float* s5, f16* d5, int n5) {
    int start = (blockIdx.x * 256 + threadIdx.x) * 8;
    int stride = gridDim.x * 2048;
    const float* ss[6] = {s0, s1, s2, s3, s4, s5};
    f16* dd[6] = {d0, d1, d2, d3, d4, d5};
    int nn[6] = {n0, n1, n2, n3, n4, n5};
    #pragma unroll
    for (int seg = 0; seg < 6; ++seg) {
        const float* s = ss[seg]; f16* d = dd[seg]; int n = nn[seg];
        for (int i = start; i < n; i += stride) {
            float4 v0 = *(const float4*)(s + i);
            float4 v1 = *(const float4*)(s + i + 4);
            f16x8 h = {(f16)v0.x, (f16)v0.y, (f16)v0.z, (f16)v0.w,
                       (f16)v1.x, (f16)v1.y, (f16)v1.z, (f16)v1.w};
            *(f16x8*)(d + i) = h;
        }
    }
}

// ---------------------------------------------------------------------------
// Embedding -> f16 residual stream
__global__ __launch_bounds__(256) void k_embed(const int* __restrict__ data,
                                               const float* __restrict__ emb,
                                               f16* __restrict__ xh) {
    int i4 = (blockIdx.x * 256 + threadIdx.x) * 4;
    if (i4 >= T_ * B_ * D_) return;
    int d  = i4 & (D_ - 1);
    int tb = i4 >> 9;
    float4 v = *(const float4*)(emb + (size_t)data[tb] * D_ + d);
    f16x4 h = {(f16)v.x, (f16)v.y, (f16)v.z, (f16)v.w};
    *(f16x4*)(xh + i4) = h;
}

// ---------------------------------------------------------------------------
__global__ __launch_bounds__(256) void k_posemb(f16* __restrict__ r, int qlen) {
    int p = blockIdx.x;
    int k = threadIdx.x;
    float pos = (float)(qlen - 1 - p);
    float inv = exp2f((float)k * -0.05190512648f);   // 10000^(-k/256)
    float ang = pos * inv;
    r[(size_t)p * D_ + k]       = (f16)sinf(ang);
    r[(size_t)p * D_ + 256 + k] = (f16)cosf(ang);
}

// ---------------------------------------------------------------------------
// MFMA fp16 GEMM, m97 1-phase structure + XCD-chunked swizzle + optional
// split-K over blockIdx.z (f16 partial slabs; bias by z==0 only; no ACT).
template<int BM, int BN, int OUT16, int ACT>
__global__ __launch_bounds__(256) void k_gemm(const f16* __restrict__ X, int lda,
                                              const f16* __restrict__ W,
                                              const float* __restrict__ bias,
                                              void* __restrict__ Yv,
                                              int M, int N, int K) {
    __shared__ f16 As[BM * 64];
    __shared__ f16 Bs[BN * 64];
    const int tid = threadIdx.x, w = tid >> 6, lane = tid & 63;
    const int l16 = lane & 15, lg = lane >> 4;
    int nwg = gridDim.x * gridDim.y;
    int bid = blockIdx.y * gridDim.x + blockIdx.x;
    if ((nwg & 7) == 0) bid = (bid & 7) * (nwg >> 3) + (bid >> 3);   // XCD chunked
    const int bm = (bid % gridDim.x) * BM, bn = (bid / gridDim.x) * BN;
    const int Kz = K / gridDim.z;
    const int kbeg = blockIdx.z * Kz, kend = kbeg + Kz;
    const size_t zofs = (size_t)blockIdx.z * M * N;
    const int lrow = lane >> 3, lcol = (lane & 7) * 8;
    constexpr int AI = BM / 32;
    constexpr int BI = BN / 32;
    constexpr int MI = (BN == 128) ? 4 : BM / 32;
    constexpr int NJ = 2;
    const int rbase = (BN == 128) ? 0 : (w >> 1) * (BM / 2);
    const int cbase = (BN == 128) ? w * 32 : (w & 1) * 32;
    const f32x4 z4 = {0.f, 0.f, 0.f, 0.f};
    f32x4 acc[MI][NJ];
    #pragma unroll
    for (int i = 0; i < MI; ++i)
        #pragma unroll
        for (int j = 0; j < NJ; ++j) acc[i][j] = z4;

    for (int k0 = kbeg; k0 < kend; k0 += 64) {
        __syncthreads();
        #pragma unroll
        for (int u = 0; u < AI; ++u) {
            int rb = w * (BM / 4) + u * 8;
            gload16(X + (size_t)(bm + rb + lrow) * lda + k0 + lcol, &As[rb * 64]);
        }
        #pragma unroll
        for (int u = 0; u < BI; ++u) {
            int rb = w * (BN / 4) + u * 8;
            gload16(W + (size_t)(bn + rb + lrow) * K + k0 + lcol, &Bs[rb * 64]);
        }
        __syncthreads();
        __builtin_amdgcn_s_setprio(1);
        #pragma unroll
        for (int h = 0; h < 2; ++h) {
            f16x8 af[MI], bf[NJ];
            #pragma unroll
            for (int i = 0; i < MI; ++i)
                af[i] = *(const f16x8*)&As[(rbase + i * 16 + l16) * 64 + h * 32 + lg * 8];
            #pragma unroll
            for (int j = 0; j < NJ; ++j)
                bf[j] = *(const f16x8*)&Bs[(cbase + j * 16 + l16) * 64 + h * 32 + lg * 8];
            #pragma unroll
            for (int i = 0; i < MI; ++i)
                #pragma unroll
                for (int j = 0; j < NJ; ++j)
                    acc[i][j] = __builtin_amdgcn_mfma_f32_16x16x32_f16(af[i], bf[j], acc[i][j], 0, 0, 0);
        }
        __builtin_amdgcn_s_setprio(0);
    }
    const bool dob = bias && (blockIdx.z == 0);
    #pragma unroll
    for (int i = 0; i < MI; ++i) {
        #pragma unroll
        for (int r = 0; r < 4; ++r) {
            int row = bm + rbase + i * 16 + lg * 4 + r;
            if (row >= M) continue;
            int colb = bn + cbase + l16;
            #pragma unroll
            for (int j = 0; j < NJ; ++j) {
                float v = acc[i][j][r];
                if (dob) v += bias[colb + j * 16];
                if (ACT) v = fmaxf(v, 0.f);
                if (OUT16) ((f16*)Yv)[zofs + (size_t)row * N + colb + j * 16] = (f16)v;
                else       ((float*)Yv)[(size_t)row * N + colb + j * 16] = v;
            }
        }
    }
}

// ---------------------------------------------------------------------------
// LayerNorm over f16 residual stream: xh = LN(xh + sum_s add[s]) * g + b.
__global__ __launch_bounds__(256) void k_ln(f16* __restrict__ xh,
                                            const f16* __restrict__ add,
                                            int nadd, int astr,
                                            const float* __restrict__ g,
                                            const float* __restrict__ b,
                                            int rows) {
    int row = blockIdx.x * 4 + (threadIdx.x >> 6);
    if (row >= rows) return;
    int lane = threadIdx.x & 63;
    f16* xr = xh + (size_t)row * D_ + lane * 8;
    float v[8];
    {
        f16x8 a = *(const f16x8*)xr;
        #pragma unroll
        for (int u = 0; u < 8; ++u) v[u] = (float)a[u];
    }
    const f16* ap = add + (size_t)row * D_ + lane * 8;
    for (int s = 0; s < nadd; ++s) {
        f16x8 a = *(const f16x8*)(ap + (size_t)s * astr);
        #pragma unroll
        for (int u = 0; u < 8; ++u) v[u] += (float)a[u];
    }
    float sm = 0.f, sq = 0.f;
    #pragma unroll
    for (int u = 0; u < 8; ++u) { sm += v[u]; sq += v[u] * v[u]; }
    #pragma unroll
    for (int off = 1; off < 64; off <<= 1) {
        sm += __shfl_xor(sm, off, 64);
        sq += __shfl_xor(sq, off, 64);
    }
    float mean = sm * (1.f / (float)D_);
    float var  = sq * (1.f / (float)D_) - mean * mean;
    float rs   = rsqrtf(var + 1e-5f);
    const float* gp = g + lane * 8;
    const float* bp = b + lane * 8;
    float4 g0 = *(const float4*)gp, g1 = *(const float4*)(gp + 4);
    float4 b0 = *(const float4*)bp, b1 = *(const float4*)(bp + 4);
    float gg[8] = {g0.x, g0.y, g0.z, g0.w, g1.x, g1.y, g1.z, g1.w};
    float bb[8] = {b0.x, b0.y, b0.z, b0.w, b1.x, b1.y, b1.z, b1.w};
    f16x8 hv;
    #pragma unroll
    for (int u = 0; u < 8; ++u) hv[u] = (f16)((v[u] - mean) * rs * gg[u] + bb[u]);
    *(f16x8*)xr = hv;
}

// ---------------------------------------------------------------------------
// Fused downsample (mean-pool + null row) + LayerNorm over f16 stream.
__global__ __launch_bounds__(256) void k_downln(const f16* __restrict__ xh,
                                                const float* __restrict__ nullg,
                                                const float* __restrict__ g,
                                                const float* __restrict__ bi,
                                                f16* __restrict__ xsh) {
    int row = blockIdx.x * 4 + (threadIdx.x >> 6);
    if (row >= (S_ + 1) * B_) return;
    int lane = threadIdx.x & 63;
    int s = row >> 2, b = row & 3;
    float v[8];
    if (s == 0) {
        const float* np = nullg + lane * 8;
        float4 a0 = *(const float4*)np, a1 = *(const float4*)(np + 4);
        v[0] = a0.x; v[1] = a0.y; v[2] = a0.z; v[3] = a0.w;
        v[4] = a1.x; v[5] = a1.y; v[6] = a1.z; v[7] = a1.w;
    } else {
        int t0 = (s - 1) * 4;
        #pragma unroll
        for (int u = 0; u < 8; ++u) v[u] = 0.f;
        #pragma unroll
        for (int k = 0; k < 4; ++k) {
            f16x8 a = *(const f16x8*)(xh + ((size_t)(t0 + k) * B_ + b) * D_ + lane * 8);
            #pragma unroll
            for (int u = 0; u < 8; ++u) v[u] += (float)a[u];
        }
        #pragma unroll
        for (int u = 0; u < 8; ++u) v[u] *= 0.25f;
    }
    float sm = 0.f, sq = 0.f;
    #pragma unroll
    for (int u = 0; u < 8; ++u) { sm += v[u]; sq += v[u] * v[u]; }
    #pragma unroll
    for (int off = 1; off < 64; off <<= 1) {
        sm += __shfl_xor(sm, off, 64);
        sq += __shfl_xor(sq, off, 64);
    }
    float mean = sm * (1.f / (float)D_);
    float var  = sq * (1.f / (float)D_) - mean * mean;
    float rs   = rsqrtf(var + 1e-5f);
    f16x8 hv;
    #pragma unroll
    for (int u = 0; u < 8; ++u)
        hv[u] = (f16)((v[u] - mean) * rs * g[lane * 8 + u] + bi[lane * 8 + u]);
    *(f16x8*)(xsh + (size_t)row * D_ + lane * 8) = hv;
}

// Upsample + residual on f16 stream
__global__ __launch_bounds__(256) void k_up(f16* __restrict__ xh,
                                            const f16* __restrict__ xsh) {
    int i8 = (blockIdx.x * 256 + threadIdx.x) * 8;
    if (i8 >= T_ * B_ * D_) return;
    int d  = i8 & (D_ - 1);
    int tb = i8 >> 9;
    int t = tb >> 2, b = tb & 3;
    int seg = (t + 1) >> 2;
    f16x8 a = *(const f16x8*)(xh + i8);
    f16x8 u2 = *(const f16x8*)(xsh + ((size_t)seg * B_ + b) * D_ + d);
    f16x8 o;
    #pragma unroll
    for (int u = 0; u < 8; ++u) o[u] = (f16)((float)a[u] + (float)u2[u]);
    *(f16x8*)(xh + i8) = o;
}

// ---------------------------------------------------------------------------
// MFMA flash attention v8: R11 structure + (a) causal mask hoisted to the
// diagonal chunk only (wave-uniform branch; chunk t needs masking iff t==it,
// which also covers the Q=257 row-boundary), (b) f16 partial acc slabs.
__global__ __launch_bounds__(256) void k_attn(f16* __restrict__ qkv,
                                              const f16* __restrict__ rkb,
                                              int ldr,
                                              const float* __restrict__ rwb,
                                              const float* __restrict__ rrb,
                                              int Q, f16* __restrict__ pacc,
                                              float* __restrict__ psums) {
    __shared__ f16 RKs[192 * 64];
    __shared__ f16 Ks[64 * 64];
    __shared__ f16 Vt[64 * 72];
    __shared__ f16 Pl[4][16 * 72];
    f16* Qw = RKs;
    f16* Qr = RKs + 4096;

    int it, t0, t1, b, n;
    bool partial;
    int idxp;
    {
        int p = blockIdx.y * gridDim.x + blockIdx.x;
        int xcd = p & 7, qq = p >> 3;
        b = xcd >> 1;
        n = (xcd & 1) * 4 + (qq & 3);
        int slot = qq >> 2;
        if (Q == 1024) {
            it = cIT[slot]; t0 = cT0[slot]; t1 = cT1[slot];
            partial = (it >= 8);
            idxp = (b * 8 + n) * 8 + (it - 8);
        } else {           // Q == 257, grid (8,32)
            it = cIT2[slot]; t0 = cT02[slot]; t1 = cT12[slot];
            partial = (it >= 2);
            idxp = (b * 8 + n) * 3 + (it - 2);
        }
    }
    const int i0 = it * 64;
    const int tid = threadIdx.x, w = tid >> 6, lane = tid & 63;
    const int l16 = lane & 15, lg = lane >> 4;
    const int xsw = (l16 & 7) << 3;
    const int gr8 = lane >> 3;
    const int gsl = ((lane & 7) ^ gr8) * 8;
    const int vjj = tid >> 2, vdb = (tid & 3) * 16;
    const int wb = 48 - w * 16;
    const f32x4 z4 = {0.f, 0.f, 0.f, 0.f};

    {   // stage Q (+biases) into RK alias, swizzled
        int row = tid >> 2, dq = (tid & 3) * 16;
        const f16* qp = qkv + ((size_t)(i0 + row) * B_ + b) * 1536 + n * 64 + dq;
        f16x8 q0 = *(const f16x8*)qp, q1 = *(const f16x8*)(qp + 8);
        int rsw = (row & 7) << 3;
        #pragma unroll
        for (int u = 0; u < 8; ++u) {
            float qa = (float)q0[u], qb2 = (float)q1[u];
            Qw[row * 64 + ((dq + u) ^ rsw)]     = (f16)(qa + rwb[n * 64 + dq + u]);
            Qw[row * 64 + ((dq + 8 + u) ^ rsw)] = (f16)(qb2 + rwb[n * 64 + dq + 8 + u]);
            Qr[row * 64 + ((dq + u) ^ rsw)]     = (f16)(qa + rrb[n * 64 + dq + u]);
            Qr[row * 64 + ((dq + 8 + u) ^ rsw)] = (f16)(qb2 + rrb[n * 64 + dq + 8 + u]);
        }
    }
    __syncthreads();
    f16x8 aqw[2], aqr[2];
    #pragma unroll
    for (int h = 0; h < 2; ++h) {
        aqw[h] = *(const f16x8*)&Qw[(w * 16 + l16) * 64 + ((h * 32 + lg * 8) ^ xsw)];
        aqr[h] = *(const f16x8*)&Qr[(w * 16 + l16) * 64 + ((h * 32 + lg * 8) ^ xsw)];
    }
    __syncthreads();

    const long long pb = (long long)Q - 64 - i0;
    #pragma unroll
    for (int u = 0; u < 4; ++u) {
        int rb = w * 32 + u * 8;
        long long p = pb + t0 * 64 + rb + gr8;
        gload16(rkb + p * ldr + n * 64 + gsl, &RKs[rb * 64]);
    }
    #pragma unroll
    for (int u = 0; u < 2; ++u) {
        int rb = w * 16 + u * 8;
        gload16(qkv + ((size_t)(t0 * 64 + rb + gr8) * B_ + b) * 1536 + 512 + n * 64 + gsl,
                &Ks[rb * 64]);
    }
    f16x8 vr0, vr1;
    {
        const f16* vp = qkv + ((size_t)(t0 * 64 + vjj) * B_ + b) * 1536 + 1024 + n * 64 + vdb;
        vr0 = *(const f16x8*)vp; vr1 = *(const f16x8*)(vp + 8);
    }

    f32x4 acc[4]; acc[0] = z4; acc[1] = z4; acc[2] = z4; acc[3] = z4;
    float psum[4] = {0.f, 0.f, 0.f, 0.f};
    int base = 0;

    for (int t = t0; t < t1; ++t) {
        const int j0 = t * 64;
        __syncthreads();   // A
        #pragma unroll
        for (int u = 0; u < 8; ++u) {
            Vt[(vdb + u) * 72 + (vjj ^ ((u & 7) << 3))]     = vr0[u];
            Vt[(vdb + 8 + u) * 72 + (vjj ^ ((u & 7) << 3))] = vr1[u];
        }
        if (t + 1 < t1) {
            int sb = base + 128; if (sb >= 192) sb -= 192;
            #pragma unroll
            for (int u = 0; u < 2; ++u) {
                int rb = w * 16 + u * 8;
                long long p = pb + j0 + 128 + rb + gr8;
                gload16(rkb + p * ldr + n * 64 + gsl, &RKs[(sb + rb) * 64]);
            }
        }
        f32x4 s1[4]; s1[0] = z4; s1[1] = z4; s1[2] = z4; s1[3] = z4;
        __builtin_amdgcn_s_setprio(1);
        #pragma unroll
        for (int f = 0; f < 4; ++f)
            #pragma unroll
            for (int h = 0; h < 2; ++h) {
                f16x8 bv = *(const f16x8*)&Ks[(f * 16 + l16) * 64 + ((h * 32 + lg * 8) ^ xsw)];
                s1[f] = __builtin_amdgcn_mfma_f32_16x16x32_f16(aqw[h], bv, s1[f], 0, 0, 0);
            }
        __builtin_amdgcn_s_setprio(0);
        if (t + 1 < t1) {
            const f16* vp = qkv + ((size_t)(j0 + 64 + vjj) * B_ + b) * 1536 + 1024 + n * 64 + vdb;
            vr0 = *(const f16x8*)vp; vr1 = *(const f16x8*)(vp + 8);
        }
        f32x4 s2[5]; s2[0] = z4; s2[1] = z4; s2[2] = z4; s2[3] = z4; s2[4] = z4;
        __builtin_amdgcn_s_setprio(1);
        #pragma unroll
        for (int f = 0; f < 5; ++f) {
            int slot = base + wb + f * 16 + l16; if (slot >= 192) slot -= 192;
            #pragma unroll
            for (int h = 0; h < 2; ++h) {
                f16x8 bv = *(const f16x8*)&RKs[slot * 64 + ((h * 32 + lg * 8) ^ xsw)];
                s2[f] = __builtin_amdgcn_mfma_f32_16x16x32_f16(aqr[h], bv, s2[f], 0, 0, 0);
            }
        }
        __builtin_amdgcn_s_setprio(0);
        // deferred softmax; mask only on the diagonal chunk (t == it)
        if (t == it) {
            #pragma unroll
            for (int r = 0; r < 4; ++r) {
                const int q = lg * 4 + r;
                const int iq = i0 + w * 16 + q;
                const int src = (lane & 48) | ((l16 + 15 - q) & 15);
                float g0 = __shfl(s2[0][r], src, 64);
                float g1 = __shfl(s2[1][r], src, 64);
                float g2 = __shfl(s2[2][r], src, 64);
                float g3 = __shfl(s2[3][r], src, 64);
                float g4 = __shfl(s2[4][r], src, 64);
                const bool hi = l16 > q;
                float sv[4];
                sv[0] = (s1[0][r] + (hi ? g1 : g0)) * 0.125f;
                sv[1] = (s1[1][r] + (hi ? g2 : g1)) * 0.125f;
                sv[2] = (s1[2][r] + (hi ? g3 : g2)) * 0.125f;
                sv[3] = (s1[3][r] + (hi ? g4 : g3)) * 0.125f;
                #pragma unroll
                for (int h = 0; h < 4; ++h) {
                    int j = j0 + h * 16 + l16;
                    if (j > iq || j >= Q) sv[h] = -1e30f;
                }
                float p0 = __expf(sv[0]), p1 = __expf(sv[1]);
                float p2 = __expf(sv[2]), p3 = __expf(sv[3]);
                psum[r] += (p0 + p1) + (p2 + p3);
                Pl[w][q * 72 + l16]      = (f16)p0;
                Pl[w][q * 72 + 16 + l16] = (f16)p1;
                Pl[w][q * 72 + 32 + l16] = (f16)p2;
                Pl[w][q * 72 + 48 + l16] = (f16)p3;
            }
        } else {
            #pragma unroll
            for (int r = 0; r < 4; ++r) {
                const int q = lg * 4 + r;
                const int src = (lane & 48) | ((l16 + 15 - q) & 15);
                float g0 = __shfl(s2[0][r], src, 64);
                float g1 = __shfl(s2[1][r], src, 64);
                float g2 = __shfl(s2[2][r], src, 64);
                float g3 = __shfl(s2[3][r], src, 64);
                float g4 = __shfl(s2[4][r], src, 64);
                const bool hi = l16 > q;
                float p0 = __expf((s1[0][r] + (hi ? g1 : g0)) * 0.125f);
                float p1 = __expf((s1[1][r] + (hi ? g2 : g1)) * 0.125f);
                float p2 = __expf((s1[2][r] + (hi ? g3 : g2)) * 0.125f);
                float p3 = __expf((s1[3][r] + (hi ? g4 : g3)) * 0.125f);
                psum[r] += (p0 + p1) + (p2 + p3);
                Pl[w][q * 72 + l16]      = (f16)p0;
                Pl[w][q * 72 + 16 + l16] = (f16)p1;
                Pl[w][q * 72 + 32 + l16] = (f16)p2;
                Pl[w][q * 72 + 48 + l16] = (f16)p3;
            }
        }
        __syncthreads();   // B
        f16x8 pa0 = *(const f16x8*)&Pl[w][l16 * 72 + lg * 8];
        f16x8 pa1 = *(const f16x8*)&Pl[w][l16 * 72 + 32 + lg * 8];
        __builtin_amdgcn_s_setprio(1);
        #pragma unroll
        for (int f = 0; f < 4; ++f) {
            f16x8 bv0 = *(const f16x8*)&Vt[(f * 16 + l16) * 72 + ((lg * 8) ^ xsw)];
            acc[f] = __builtin_amdgcn_mfma_f32_16x16x32_f16(pa0, bv0, acc[f], 0, 0, 0);
            f16x8 bv1 = *(const f16x8*)&Vt[(f * 16 + l16) * 72 + ((32 + lg * 8) ^ xsw)];
            acc[f] = __builtin_amdgcn_mfma_f32_16x16x32_f16(pa1, bv1, acc[f], 0, 0, 0);
        }
        __builtin_amdgcn_s_setprio(0);
        if (t + 1 < t1) {
            #pragma unroll
            for (int u = 0; u < 2; ++u) {
                int rb = w * 16 + u * 8;
                gload16(qkv + ((size_t)(j0 + 64 + rb + gr8) * B_ + b) * 1536 + 512 + n * 64 + gsl,
                        &Ks[rb * 64]);
            }
        }
        base += 64; if (base >= 192) base -= 192;
    }
    if (partial) {
        f16* Pp = pacc + (size_t)idxp * 8192 + (t0 ? 4096 : 0);
        float* Sp = psums + idxp * 128 + (t0 ? 64 : 0);
        #pragma unroll
        for (int r = 0; r < 4; ++r) {
            float ps = psum[r];
            ps += __shfl_xor(ps, 1, 64);
            ps += __shfl_xor(ps, 2, 64);
            ps += __shfl_xor(ps, 4, 64);
            ps += __shfl_xor(ps, 8, 64);
            int row = w * 16 + lg * 4 + r;
            #pragma unroll
            for (int f = 0; f < 4; ++f)
                Pp[row * 64 + f * 16 + l16] = (f16)acc[f][r];
            if (l16 == 0) Sp[row] = ps;
        }
    } else {
        #pragma unroll
        for (int r = 0; r < 4; ++r) {
            float ps = psum[r];
            ps += __shfl_xor(ps, 1, 64);
            ps += __shfl_xor(ps, 2, 64);
            ps += __shfl_xor(ps, 4, 64);
            ps += __shfl_xor(ps, 8, 64);
            int i = i0 + w * 16 + lg * 4 + r;
            if (i < Q) {
                float inv = 1.f / ps;
                f16* op = qkv + ((size_t)i * B_ + b) * 1536 + n * 64;
                #pragma unroll
                for (int f = 0; f < 4; ++f)
                    op[f * 16 + l16] = (f16)(acc[f][r] * inv);
            }
        }
    }
}

// ---------------------------------------------------------------------------
// Combine split-attention partials: out = (accA+accB)/(psA+psB). f16 acc.
__global__ __launch_bounds__(256) void k_comb(const f16* __restrict__ pacc,
                                              const float* __restrict__ psums,
                                              f16* __restrict__ qkv,
                                              int nm, int itbase, int Q) {
    int idxp = blockIdx.x;
    int m = idxp % nm;
    int bn = idxp / nm;
    int b = bn >> 3, n = bn & 7;
    int i0 = (m + itbase) * 64;
    int row = threadIdx.x >> 2, dp = (threadIdx.x & 3) * 16;
    if (i0 + row >= Q) return;
    const f16* A  = pacc + (size_t)idxp * 8192;
    const f16* Bp = A + 4096;
    const float* Sp = psums + idxp * 128;
    float inv = 1.f / (Sp[row] + Sp[64 + row]);
    f16* op = qkv + ((size_t)(i0 + row) * B_ + b) * 1536 + n * 64 + dp;
    f16x8 a0 = *(const f16x8*)(A  + row * 64 + dp);
    f16x8 a1 = *(const f16x8*)(A  + row * 64 + dp + 8);
    f16x8 b0 = *(const f16x8*)(Bp + row * 64 + dp);
    f16x8 b1 = *(const f16x8*)(Bp + row * 64 + dp + 8);
    f16x8 o0, o1;
    #pragma unroll
    for (int u = 0; u < 8; ++u) {
        o0[u] = (f16)(((float)a0[u] + (float)b0[u]) * inv);
        o1[u] = (f16)(((float)a1[u] + (float)b1[u]) * inv);
    }
    *(f16x8*)op = o0;
    *(f16x8*)(op + 8) = o1;
}

// ---------------------------------------------------------------------------
extern "C" void kernel_launch(void* const* d_in, const int* in_sizes, int n_in,
                              void* d_out, int out_size, void* d_ws, size_t ws_size,
                              hipStream_t stream) {
    const int*   data     = (const int*)  d_in[0];
    const float* word_emb = (const float*)d_in[2];
    const float* rwb      = (const float*)d_in[3];
    const float* rrb      = (const float*)d_in[4];
    const float* nullg    = (const float*)d_in[5];
    const float* dg       = (const float*)d_in[6];
    const float* db       = (const float*)d_in[7];
    const float* qkv_w    = (const float*)d_in[8];
    const float* rk_w     = (const float*)d_in[9];
    const float* o_w      = (const float*)d_in[10];
    const float* ln1g     = (const float*)d_in[11];
    const float* ln1b     = (const float*)d_in[12];
    const float* w1       = (const float*)d_in[13];
    const float* b1       = (const float*)d_in[14];
    const float* w2       = (const float*)d_in[15];
    const float* b2       = (const float*)d_in[16];
    const float* ln2g     = (const float*)d_in[17];
    const float* ln2b     = (const float*)d_in[18];
    const float* fw       = (const float*)d_in[19];
    const float* fb       = (const float*)d_in[20];
    float* out = (float*)d_out;
    float* ws  = (float*)d_ws;

    // workspace (~92 MB), f16-only residual stream.
    // ov overlay: attn partials (pacc f16 + psums f32) and GEMM f16 tmp slabs
    // — all lifetimes disjoint within a layer.
    float* ov   = ws;                          // 2129920 f (8.52 MB)
    f16* tmph   = (f16*)ov;                    // GEMM tmp/partial slabs
    f16* pacc   = (f16*)ov;                    // attn acc partials (256*8192 h)
    float* psms = ov + 1048576;                // attn psum partials (256*128 f)
    f16* xh     = (f16*)(ov + 2129920);        // 2097152 h
    f16* xsh    = xh + 2097152;                // 589824 h
    f16* r1h    = xsh + 589824;                // 524288 h
    f16* r2h    = r1h + 524288;                // 163840 h
    f16* rkall  = r2h + 163840;                // 2623488 h
    f16* bigh   = rkall + 2623488;             // 8388608 h
    f16* qkv_wh = bigh + 8388608;              // 6291456 h
    f16* rk_wh  = qkv_wh + 6291456;            // 2097152 h
    f16* o_wh   = rk_wh + 2097152;             // 2097152 h
    f16* w1h    = o_wh + 2097152;              // 8388608 h
    f16* w2h    = w1h + 8388608;               // 8388608 h
    f16* fwh    = w2h + 8388608;               // 131072 h

    k_f2hall<<<2048, 256, 0, stream>>>(
        qkv_w, qkv_wh, L_ * 1536 * 512,
        rk_w,  rk_wh,  L_ * 512 * 512,
        o_w,   o_wh,   L_ * 512 * 512,
        w1,    w1h,    L_ * 2048 * 512,
        w2,    w2h,    L_ * 512 * 2048,
        fw,    fwh,    256 * 512);

    auto gemm = [&](const f16* Xp, int lda, const f16* Wp, const float* bp,
                    void* Yp, int M, int N, int K, int out16, int act, int splitk) {
        if (splitk > 1) {
            dim3 g((M + 31) / 32, N / 64, splitk);
            k_gemm<32, 64, 1, 0><<<g, 256, 0, stream>>>(Xp, lda, Wp, bp, Yp, M, N, K);
            return;
        }
        int b64_128 = (N % 128 == 0) ? ((M + 63) / 64) * (N / 128) : 0;
        if (b64_128 >= 768) {
            dim3 g((M + 63) / 64, N / 128);
            if (out16) {
                if (act) k_gemm<64, 128, 1, 1><<<g, 256, 0, stream>>>(Xp, lda, Wp, bp, Yp, M, N, K);
                else     k_gemm<64, 128, 1, 0><<<g, 256, 0, stream>>>(Xp, lda, Wp, bp, Yp, M, N, K);
            } else      k_gemm<64, 128, 0, 0><<<g, 256, 0, stream>>>(Xp, lda, Wp, bp, Yp, M, N, K);
            return;
        }
        int b64_64 = ((M + 63) / 64) * (N / 64);
        if (b64_64 >= 768) {
            dim3 g((M + 63) / 64, N / 64);
            if (out16) {
                if (act) k_gemm<64, 64, 1, 1><<<g, 256, 0, stream>>>(Xp, lda, Wp, bp, Yp, M, N, K);
                else     k_gemm<64, 64, 1, 0><<<g, 256, 0, stream>>>(Xp, lda, Wp, bp, Yp, M, N, K);
            } else      k_gemm<64, 64, 0, 0><<<g, 256, 0, stream>>>(Xp, lda, Wp, bp, Yp, M, N, K);
            return;
        }
        dim3 g((M + 31) / 32, N / 64);
        if (out16) {
            if (act) k_gemm<32, 64, 1, 1><<<g, 256, 0, stream>>>(Xp, lda, Wp, bp, Yp, M, N, K);
            else     k_gemm<32, 64, 1, 0><<<g, 256, 0, stream>>>(Xp, lda, Wp, bp, Yp, M, N, K);
        } else      k_gemm<32, 64, 0, 0><<<g, 256, 0, stream>>>(Xp, lda, Wp, bp, Yp, M, N, K);
    };

    k_embed<<<2048, 256, 0, stream>>>(data, word_emb, xh);
    k_posemb<<<1024, 256, 0, stream>>>(r1h, 1024);
    k_posemb<<<257, 256, 0, stream>>>(r2h, 257);

    // batched RK precompute (r is layer-invariant)
    gemm(r1h, 512, rk_wh,              nullptr, rkall,           1024, 1024, 512, 1, 0, 1);
    gemm(r1h, 512, rk_wh + 6 * 262144, nullptr, rkall + 1048576, 1024, 1024, 512, 1, 0, 1);
    gemm(r2h, 512, rk_wh + 2 * 262144, nullptr, rkall + 2097152,  257, 2048, 512, 1, 0, 1);

    auto stage = [&](f16* xbh, int Q, int lo, int hi) {
        const int M = Q * B_;
        dim3 gA = (Q == 1024) ? dim3(24, 32) : dim3(8, 32);
        dim3 gL((M + 3) / 4);
        const int sk_o  = (Q == 1024) ? 1 : 2;
        const int sk_w2 = (Q == 1024) ? 1 : 4;
        for (int i = lo; i < hi; ++i) {
            const f16* rkp; int ldr;
            if (i < 2)       { rkp = rkall + i * 512;                 ldr = 1024; }
            else if (i >= 6) { rkp = rkall + 1048576 + (i - 6) * 512; ldr = 1024; }
            else             { rkp = rkall + 2097152 + (i - 2) * 512; ldr = 2048; }
            gemm(xbh, 512, qkv_wh + (size_t)i * 786432, nullptr, bigh, M, 1536, 512, 1, 0, 1);
            k_attn<<<gA, 256, 0, stream>>>(bigh, rkp, ldr, rwb, rrb, Q, pacc, psms);
            if (Q == 1024) k_comb<<<256, 256, 0, stream>>>(pacc, psms, bigh, 8, 8, 1024);
            else           k_comb<<<96, 256, 0, stream>>>(pacc, psms, bigh, 3, 2, 257);
            gemm(bigh, 1536, o_wh + (size_t)i * 262144, nullptr, tmph, M, 512, 512, 1, 0, sk_o);
            k_ln<<<gL, 256, 0, stream>>>(xbh, tmph, sk_o, M * 512,
                                         ln1g + (size_t)i * 512, ln1b + (size_t)i * 512, M);
            gemm(xbh, 512, w1h + (size_t)i * 1048576, b1 + (size_t)i * 2048, bigh, M, 2048, 512, 1, 1, 1);
            gemm(bigh, 2048, w2h + (size_t)i * 1048576, b2 + (size_t)i * 512, tmph, M, 512, 2048, 1, 0, sk_w2);
            k_ln<<<gL, 256, 0, stream>>>(xbh, tmph, sk_w2, M * 512,
                                         ln2g + (size_t)i * 512, ln2b + (size_t)i * 512, M);
        }
    };

    stage(xh, 1024, 0, 2);                                       // pre
    k_downln<<<257, 256, 0, stream>>>(xh, nullg, dg, db, xsh);
    stage(xsh, S_ + 1, 2, 6);                                    // shortened
    k_up<<<1024, 256, 0, stream>>>(xh, xsh);                     // upsample + residual
    stage(xh, 1024, 6, 8);                                       // post
    gemm(xh, 512, fwh, fb, out, T_ * B_, V_, 512, 0, 0, 1);      // logits
}